// Round 2
// baseline (3925.371 us; speedup 1.0000x reference)
//
#include <hip/hip_runtime.h>
#include <math.h>

#define N   96
#define N2  9216
#define NPAIRS (N*N*N/2)   // 442368 pairs of T-rows

#define M_COLD 64
#define M_WARM 40

// d_ws layout (float offsets)
#define OFF_V   0                  // 96: v = A@u (unnormalized Cocc column) -> density D = v v^T
#define OFF_U   128                // 96: u (normalized eigvec of Fp) for warm start
#define OFF_F   256                // 9216: F
#define OFF_M1  (OFF_F  + N2)      // 9216: M1 = F@A
#define OFF_FP  (OFF_M1 + N2)      // 9216: Fp = A@F@A
#define OFF_T   (OFF_FP + N2)      // 884736: T[p][q][r] = sum_s G[p,q,r,s] v_s
// total = 256 + 3*9216 + 884736 floats  ≈ 3.66 MB

// ---------------------------------------------------------------------------
// T[p,q,r] = sum_s G[p,q,r,s] * v[s].  Each wave handles 2 consecutive rows
// (192 floats = 768B contiguous): lane loads elems {l, l+64, l+128}.
// ---------------------------------------------------------------------------
__global__ __launch_bounds__(256)
void k_contract(const float* __restrict__ G, const float* __restrict__ v,
                float* __restrict__ T)
{
    __shared__ float vs[N];
    const int tid = threadIdx.x;
    if (tid < N) vs[tid] = v[tid];
    __syncthreads();
    const int lane  = tid & 63;
    const int gwave = (int)((blockIdx.x * blockDim.x + tid) >> 6);
    const int nw    = (int)((gridDim.x * blockDim.x) >> 6);
    const float v0 = vs[lane];                                // flat l      -> row0, s=l
    const float v1 = (lane < 32) ? vs[lane + 64] : vs[lane - 32]; // flat l+64
    const float v2 = vs[lane + 32];                           // flat l+128  -> row1, s=l+32
    for (int pr = gwave; pr < NPAIRS; pr += nw) {
        const float* g = G + (size_t)pr * 192;
        float x0 = g[lane], x1 = g[lane + 64], x2 = g[lane + 128];
        float s0 = x0 * v0;
        float s1 = x2 * v2;
        if (lane < 32) s0 += x1 * v1; else s1 += x1 * v1;
        #pragma unroll
        for (int o = 32; o; o >>= 1) { s0 += __shfl_xor(s0, o); s1 += __shfl_xor(s1, o); }
        if (lane == 0) { T[2*(size_t)pr] = s0; T[2*(size_t)pr + 1] = s1; }
    }
}

// ---------------------------------------------------------------------------
// Block p: stage T[p] tile, J[p,:] = T[p,q,:]·v, K[p,:] = v·T[p,:,q],
// F[p,:] = H + 2J - K, M1[p,:] = F[p,:] @ A.
// ---------------------------------------------------------------------------
__global__ __launch_bounds__(256)
void k_buildF(const float* __restrict__ T, const float* __restrict__ v,
              const float* __restrict__ H, const float* __restrict__ A,
              float* __restrict__ F, float* __restrict__ M1, int zeroD)
{
    __shared__ float Ts[N * 97];   // padded: stride 97 avoids bank conflicts on column reads
    __shared__ float vs[N];
    __shared__ float Frow[N];
    const int p = blockIdx.x, tid = threadIdx.x;
    if (!zeroD) {
        if (tid < N) vs[tid] = v[tid];
        for (int i = tid; i < N2; i += 256) {
            int q = i / N, r = i - q * N;
            Ts[q * 97 + r] = T[(size_t)p * N2 + i];
        }
    }
    __syncthreads();
    if (tid < N) {
        const int q = tid;
        float J = 0.f, K = 0.f;
        if (!zeroD) {
            for (int r = 0; r < N; ++r) {
                J += Ts[q * 97 + r] * vs[r];
                K += vs[r] * Ts[r * 97 + q];
            }
        }
        float f = H[p * N + q] + 2.0f * J - K;
        Frow[q] = f;
        F[p * N + q] = f;
    }
    __syncthreads();
    if (tid < N) {
        const int q = tid;
        float acc = 0.f;
        for (int k = 0; k < N; ++k) acc += Frow[k] * A[k * N + q];
        M1[p * N + q] = acc;
    }
}

// Fp[p,:] = A[p,:] @ M1
__global__ __launch_bounds__(128)
void k_AM(const float* __restrict__ A, const float* __restrict__ M1,
          float* __restrict__ Fp)
{
    __shared__ float Ar[N];
    const int p = blockIdx.x, tid = threadIdx.x;
    if (tid < N) Ar[tid] = A[p * N + tid];
    __syncthreads();
    if (tid < N) {
        float acc = 0.f;
        for (int k = 0; k < N; ++k) acc += Ar[k] * M1[k * N + tid];
        Fp[p * N + tid] = acc;
    }
}

// ---------------------------------------------------------------------------
// Single-block eigensolver: Lanczos (CGS2 reorth) for the LOWEST eigenpair of
// Fp, then v = A@u, E = v^T (F+H) v + Enuc.  384 threads = 6 waves.
// ---------------------------------------------------------------------------
__global__ __launch_bounds__(384)
void k_eig(const float* __restrict__ Fp, const float* __restrict__ A,
           const float* __restrict__ F, const float* __restrict__ H,
           const float* __restrict__ Enuc,
           float* __restrict__ v_ws, float* __restrict__ u_ws,
           float* __restrict__ out, int cold, int m_max, int writeE)
{
    __shared__ float  Fs[N * 97];          // 37248 B
    __shared__ float  V[M_COLD][N];        // 24576 B
    __shared__ float  w[N];
    __shared__ float  vn[N];
    __shared__ float  alpha[M_COLD + 1];
    __shared__ float  beta[M_COLD + 1];
    __shared__ float  dred[M_COLD];
    __shared__ float  wsml[M_COLD];
    __shared__ double cp[M_COLD];
    __shared__ double dp[M_COLD];
    __shared__ float  s_scal[4];
    __shared__ int    s_meff, s_done;

    const int tid  = threadIdx.x;
    const int lane = tid & 63;
    const int wv   = tid >> 6;

    for (int i = tid; i < N2; i += 384) {
        int r = i / N, c = i - r * N;
        Fs[r * 97 + c] = Fp[i];
    }
    if (tid < N) {
        float x;
        if (cold) {   // deterministic generic start vector
            unsigned r = (unsigned)tid * 1103515245u + 12345u;
            r ^= r >> 13; r *= 2654435761u; r ^= r >> 16;
            x = (float)(r & 0xFFFFu) * (1.0f / 65536.0f) - 0.45f;
        } else {
            x = u_ws[tid];
        }
        w[tid] = x;
    }
    if (tid == 0) { s_meff = m_max; s_done = 0; beta[0] = 0.f; }
    __syncthreads();
    if (wv == 0) {
        float a = w[lane] * w[lane];
        if (lane < 32) a += w[lane + 64] * w[lane + 64];
        #pragma unroll
        for (int o = 32; o; o >>= 1) a += __shfl_xor(a, o);
        if (lane == 0) s_scal[0] = sqrtf(a);
    }
    __syncthreads();
    if (tid < N) V[0][tid] = w[tid] / s_scal[0];
    __syncthreads();

    // ---------------- Lanczos ----------------
    for (int j = 0; j < m_max; ++j) {
        if (s_done) break;                       // uniform (read after sync)
        {   // w = Fs * V[j]
            const int i = tid >> 2, c = tid & 3;
            const float* qv  = &V[j][0];
            const float* row = &Fs[i * 97 + c * 24];
            float p = 0.f;
            #pragma unroll
            for (int k = 0; k < 24; ++k) p += row[k] * qv[c * 24 + k];
            p += __shfl_xor(p, 1);
            p += __shfl_xor(p, 2);
            if (c == 0) w[i] = p;
        }
        __syncthreads();
        if (wv == 0) {   // alpha[j] = V[j]·w
            float a = w[lane] * V[j][lane];
            if (lane < 32) a += w[lane + 64] * V[j][lane + 64];
            #pragma unroll
            for (int o = 32; o; o >>= 1) a += __shfl_xor(a, o);
            if (lane == 0) alpha[j] = a;
        }
        __syncthreads();
        if (j + 1 == m_max) break;               // uniform; alpha[j] recorded
        if (tid < N) {
            float x = w[tid] - alpha[j] * V[j][tid];
            if (j > 0) x -= beta[j] * V[j - 1][tid];
            w[tid] = x;
        }
        __syncthreads();
        for (int pass = 0; pass < 2; ++pass) {   // CGS2 full reorth
            for (int k = wv; k <= j; k += 6) {
                float a = V[k][lane] * w[lane];
                if (lane < 32) a += V[k][lane + 64] * w[lane + 64];
                #pragma unroll
                for (int o = 32; o; o >>= 1) a += __shfl_xor(a, o);
                if (lane == 0) dred[k] = a;
            }
            __syncthreads();
            if (tid < N) {
                float x = w[tid];
                for (int k = 0; k <= j; ++k) x -= dred[k] * V[k][tid];
                w[tid] = x;
            }
            __syncthreads();
        }
        if (wv == 0) {   // beta[j+1] = ||w||
            float a = w[lane] * w[lane];
            if (lane < 32) a += w[lane + 64] * w[lane + 64];
            #pragma unroll
            for (int o = 32; o; o >>= 1) a += __shfl_xor(a, o);
            if (lane == 0) s_scal[0] = sqrtf(a);
        }
        __syncthreads();
        float b = s_scal[0];
        if (tid == 0) beta[j + 1] = b;
        if (b < 1e-5f) {                         // breakdown => invariant subspace
            if (tid == 0) { s_meff = j + 1; s_done = 1; }
        } else {
            if (tid < N) V[j + 1][tid] = w[tid] / b;
        }
        __syncthreads();
    }
    __syncthreads();
    const int m = s_meff;

    // ------------- smallest eigenvalue of tridiag via parallel bisection -------------
    if (wv == 0) {
        float lo_l = 3e38f, hid = 3e38f;
        if (lane < m) {
            float bl = (lane > 0) ? fabsf(beta[lane]) : 0.f;
            float br = (lane + 1 < m) ? fabsf(beta[lane + 1]) : 0.f;
            lo_l = alpha[lane] - bl - br;
            hid  = alpha[lane];                  // lambda_min <= min diag
        }
        #pragma unroll
        for (int o = 32; o; o >>= 1) {
            lo_l = fminf(lo_l, __shfl_xor(lo_l, o));
            hid  = fminf(hid,  __shfl_xor(hid,  o));
        }
        float lo = lo_l - 1e-5f, hi = hid + 1e-5f;
        for (int round = 0; round < 4; ++round) {
            float x = lo + (hi - lo) * (float)(lane + 1) * (1.0f / 65.0f);
            int cnt = 0;
            float q = alpha[0] - x;
            if (q < 0.f) cnt++;
            for (int i = 1; i < m; ++i) {
                if (fabsf(q) < 1e-25f) q = (q < 0.f) ? -1e-25f : 1e-25f;
                float bi = beta[i];
                q = (alpha[i] - x) - bi * bi / q;
                if (q < 0.f) cnt++;
            }
            unsigned long long mask = __ballot(cnt >= 1);
            if (mask == 0ull) {
                lo = lo + (hi - lo) * (64.0f / 65.0f);
            } else {
                int f = __builtin_ctzll(mask);
                float xf  = lo + (hi - lo) * (float)(f + 1) * (1.0f / 65.0f);
                float xfm = lo + (hi - lo) * (float)(f)     * (1.0f / 65.0f);
                hi = xf; lo = xfm;
            }
        }
        if (lane == 0) s_scal[1] = 0.5f * (lo + hi);
    }
    __syncthreads();

    // ------------- tridiagonal inverse iteration (fp64 Thomas, thread 0) -----
    // Shift 1e-6 BELOW the bisection midpoint: bracket err <= ~2e-7, so the
    // shifted lam is strictly below lambda_min => T - lam is positive definite,
    // pivots >= ~1e-6, dp <= ~1e7 -> no overflow (round-1 NaN was inf here).
    if (tid == 0) {
        if (m == 1) {
            wsml[0] = 1.0f;
        } else {
            double lam = (double)s_scal[1] - 1e-6;
            for (int pass = 0; pass < 2; ++pass) {
                double b0 = (double)alpha[0] - lam;
                if (fabs(b0) < 1e-18) b0 = (b0 < 0.0) ? -1e-18 : 1e-18;
                cp[0] = (double)beta[1] / b0;
                dp[0] = (pass ? (double)wsml[0] : 1.0) / b0;
                for (int i = 1; i < m; ++i) {
                    double ai = (double)beta[i];
                    double md = ((double)alpha[i] - lam) - ai * cp[i - 1];
                    if (fabs(md) < 1e-18) md = (md < 0.0) ? -1e-18 : 1e-18;
                    cp[i] = ((i + 1 < m) ? (double)beta[i + 1] : 0.0) / md;
                    double rhs = pass ? (double)wsml[i] : 1.0;
                    dp[i] = (rhs - ai * dp[i - 1]) / md;
                }
                for (int i = m - 2; i >= 0; --i) dp[i] -= cp[i] * dp[i + 1];
                double nn = 0.0;
                for (int i = 0; i < m; ++i) nn += dp[i] * dp[i];
                if (!(nn > 0.0) || isinf(nn)) {   // paranoia fallback
                    for (int i = 0; i < m; ++i) wsml[i] = (i == 0) ? 1.0f : 0.0f;
                } else {
                    double inv = 1.0 / sqrt(nn);
                    for (int i = 0; i < m; ++i) wsml[i] = (float)(dp[i] * inv);
                }
            }
        }
    }
    __syncthreads();

    // Ritz vector u = V^T wsml
    if (tid < N) {
        float acc = 0.f;
        for (int j = 0; j < m; ++j) acc += wsml[j] * V[j][tid];
        w[tid] = acc;
    }
    __syncthreads();
    if (wv == 0) {
        float a = w[lane] * w[lane];
        if (lane < 32) a += w[lane + 64] * w[lane + 64];
        #pragma unroll
        for (int o = 32; o; o >>= 1) a += __shfl_xor(a, o);
        if (lane == 0) s_scal[2] = sqrtf(a);
    }
    __syncthreads();
    if (tid < N) {
        float un = w[tid] / s_scal[2];
        w[tid] = un;
        u_ws[tid] = un;              // warm start for next SCF iteration
    }
    __syncthreads();
    // v = A @ u  (unnormalized Cocc column; D = v v^T)
    if (tid < N) {
        float acc = 0.f;
        for (int k = 0; k < N; ++k) acc += A[tid * N + k] * w[k];
        vn[tid] = acc;
        v_ws[tid] = acc;
    }
    __syncthreads();
    // energy rows: w[i] = sum_k (F+H)[i,k] * vn[k]
    {
        const int i = tid >> 2, c = tid & 3;
        float p = 0.f;
        const int base = i * N + c * 24;
        #pragma unroll
        for (int k = 0; k < 24; ++k) p += (F[base + k] + H[base + k]) * vn[c * 24 + k];
        p += __shfl_xor(p, 1);
        p += __shfl_xor(p, 2);
        if (c == 0) w[i] = p;
    }
    __syncthreads();
    if (wv == 0) {
        float e = vn[lane] * w[lane];
        if (lane < 32) e += vn[lane + 64] * w[lane + 64];
        #pragma unroll
        for (int o = 32; o; o >>= 1) e += __shfl_xor(e, o);
        if (lane == 0 && writeE) out[0] = e + Enuc[0];
    }
}

// ---------------------------------------------------------------------------
extern "C" void kernel_launch(void* const* d_in, const int* in_sizes, int n_in,
                              void* d_out, int out_size, void* d_ws, size_t ws_size,
                              hipStream_t stream)
{
    (void)in_sizes; (void)n_in; (void)out_size; (void)ws_size;
    // inputs: D (zeros, unused), H, A, G, Enuc
    const float* H    = (const float*)d_in[1];
    const float* A    = (const float*)d_in[2];
    const float* G    = (const float*)d_in[3];
    const float* Enuc = (const float*)d_in[4];
    float* out = (float*)d_out;
    float* ws  = (float*)d_ws;
    float* v  = ws + OFF_V;
    float* u  = ws + OFF_U;
    float* F  = ws + OFF_F;
    float* M1 = ws + OFF_M1;
    float* Fp = ws + OFF_FP;
    float* T  = ws + OFF_T;

    for (int it = 0; it < 20; ++it) {
        if (it > 0) {
            k_contract<<<2048, 256, 0, stream>>>(G, v, T);
        }
        k_buildF<<<96, 256, 0, stream>>>(T, v, H, A, F, M1, it == 0 ? 1 : 0);
        k_AM<<<96, 128, 0, stream>>>(A, M1, Fp);
        k_eig<<<1, 384, 0, stream>>>(Fp, A, F, H, Enuc, v, u, out,
                                     it == 0 ? 1 : 0,
                                     it == 0 ? M_COLD : M_WARM,
                                     it == 19 ? 1 : 0);
    }
}

// Round 3
// 1709.991 us; speedup vs baseline: 2.2956x; 2.2956x over previous
//
#include <hip/hip_runtime.h>
#include <math.h>

#define N   96
#define N2  9216
#define NPAIR_SYM 4656     // 96*97/2 (p<=q) pair-blocks of G

#define M_COLD 48
#define M_WARM 16

// d_ws layout (float offsets)
#define OFF_V   0                  // 96: v = A@u (unnormalized Cocc column) -> density D = v v^T
#define OFF_U   128                // 96: u (normalized eigvec of Fp) for warm start
#define OFF_F   256                // 9216: F
#define OFF_M1  (OFF_F  + N2)      // 9216: M1 = F@A
#define OFF_FP  (OFF_M1 + N2)      // 9216: Fp = A@F@A
#define OFF_T   (OFF_FP + N2)      // 884736: T[p][q][r] = sum_s G[p,q,r,s] v_s

// ---------------------------------------------------------------------------
// T via pair symmetry G[p,q,r,s] = G[q,p,s,r]:
// one block per (p<=q): stage M = G[p,q,:,:] (36KB), then
//   T[p,q,r] = (M v)_r   and   T[q,p,s] = (M^T v)_s.
// Reads only 168MB of G per SCF iteration (vs 336MB), L3-cacheable.
// ---------------------------------------------------------------------------
__global__ __launch_bounds__(256)
void k_contract(const float* __restrict__ G, const float* __restrict__ v,
                float* __restrict__ T)
{
    __shared__ float Ms[N * 97];   // stride 97: conflict-free row AND col dots
    __shared__ float vs[N];
    const int tid = threadIdx.x;
    const int b   = blockIdx.x;
    // decode b -> (p,q), p<=q ; start(p) = p*96 - p*(p-1)/2
    int p = (int)((193.0 - sqrt(37249.0 - 8.0 * (double)b)) * 0.5);
    if (p > 95) p = 95;
    if (p < 0) p = 0;
    while (p * 96 - p * (p - 1) / 2 > b) --p;
    while ((p + 1) * 96 - (p + 1) * p / 2 <= b) ++p;
    const int q = p + (b - (p * 96 - p * (p - 1) / 2));

    if (tid < N) vs[tid] = v[tid];
    {   // stage M as float4 (96%4==0 so each float4 stays in one row)
        const float4* G4 = (const float4*)(G + (size_t)(p * N + q) * N2);
        #pragma unroll
        for (int k = tid; k < N2 / 4; k += 256) {
            float4 f = G4[k];
            int r = k / 24, s4 = k - r * 24;
            float* dst = &Ms[r * 97 + 4 * s4];
            dst[0] = f.x; dst[1] = f.y; dst[2] = f.z; dst[3] = f.w;
        }
    }
    __syncthreads();
    if (tid < N) {                 // row dot: T[p,q,tid] = sum_s M[tid][s] v[s]
        const float* row = &Ms[tid * 97];
        float acc = 0.f;
        #pragma unroll 8
        for (int s = 0; s < N; ++s) acc += row[s] * vs[s];
        T[(size_t)(p * N + q) * N + tid] = acc;
    } else if (tid < 2 * N && p != q) {  // col dot: T[q,p,s] = sum_r M[r][s] v[r]
        const int s = tid - N;
        float acc = 0.f;
        #pragma unroll 8
        for (int r = 0; r < N; ++r) acc += Ms[r * 97 + s] * vs[r];
        T[(size_t)(q * N + p) * N + s] = acc;
    }
}

// ---------------------------------------------------------------------------
// Block p: stage T[p] tile, J[p,:] = T[p,q,:]·v, K[p,:] = v·T[p,:,q],
// F[p,:] = H + 2J - K, M1[p,:] = F[p,:] @ A.
// ---------------------------------------------------------------------------
__global__ __launch_bounds__(256)
void k_buildF(const float* __restrict__ T, const float* __restrict__ v,
              const float* __restrict__ H, const float* __restrict__ A,
              float* __restrict__ F, float* __restrict__ M1, int zeroD)
{
    __shared__ float Ts[N * 97];
    __shared__ float vs[N];
    __shared__ float Frow[N];
    const int p = blockIdx.x, tid = threadIdx.x;
    if (!zeroD) {
        if (tid < N) vs[tid] = v[tid];
        for (int i = tid; i < N2; i += 256) {
            int q = i / N, r = i - q * N;
            Ts[q * 97 + r] = T[(size_t)p * N2 + i];
        }
    }
    __syncthreads();
    if (tid < N) {
        const int q = tid;
        float J = 0.f, K = 0.f;
        if (!zeroD) {
            for (int r = 0; r < N; ++r) {
                J += Ts[q * 97 + r] * vs[r];
                K += vs[r] * Ts[r * 97 + q];
            }
        }
        float f = H[p * N + q] + 2.0f * J - K;
        Frow[q] = f;
        F[p * N + q] = f;
    }
    __syncthreads();
    if (tid < N) {
        const int q = tid;
        float acc = 0.f;
        for (int k = 0; k < N; ++k) acc += Frow[k] * A[k * N + q];
        M1[p * N + q] = acc;
    }
}

// Fp[p,:] = A[p,:] @ M1
__global__ __launch_bounds__(128)
void k_AM(const float* __restrict__ A, const float* __restrict__ M1,
          float* __restrict__ Fp)
{
    __shared__ float Ar[N];
    const int p = blockIdx.x, tid = threadIdx.x;
    if (tid < N) Ar[tid] = A[p * N + tid];
    __syncthreads();
    if (tid < N) {
        float acc = 0.f;
        for (int k = 0; k < N; ++k) acc += Ar[k] * M1[k * N + tid];
        Fp[p * N + tid] = acc;
    }
}

// ---------------------------------------------------------------------------
// Single-block eigensolver: Lanczos with full CGS2 reorth (alpha folded into
// pass-1 dots: alpha[j] = <V[j], F V[j]> = dred1[j] + dred2[j]) for the
// LOWEST eigenpair of Fp, then v = A@u, E = v^T (F+H) v + Enuc.
// ---------------------------------------------------------------------------
__global__ __launch_bounds__(384)
void k_eig(const float* __restrict__ Fp, const float* __restrict__ A,
           const float* __restrict__ F, const float* __restrict__ H,
           const float* __restrict__ Enuc,
           float* __restrict__ v_ws, float* __restrict__ u_ws,
           float* __restrict__ out, int cold, int m_max, int writeE)
{
    __shared__ float  Fs[N * 97];          // 37248 B
    __shared__ float  V[M_COLD][N];        // 18432 B
    __shared__ float  w[N];
    __shared__ float  vn[N];
    __shared__ float  alpha[M_COLD + 1];
    __shared__ float  beta[M_COLD + 1];
    __shared__ float  dred[M_COLD];
    __shared__ float  wsml[M_COLD];
    __shared__ double cp[M_COLD];
    __shared__ double dp[M_COLD];
    __shared__ float  s_scal[4];
    __shared__ int    s_meff, s_done;

    const int tid  = threadIdx.x;
    const int lane = tid & 63;
    const int wv   = tid >> 6;

    for (int i = tid; i < N2; i += 384) {
        int r = i / N, c = i - r * N;
        Fs[r * 97 + c] = Fp[i];
    }
    if (tid < N) {
        float x;
        if (cold) {   // deterministic generic start vector
            unsigned r = (unsigned)tid * 1103515245u + 12345u;
            r ^= r >> 13; r *= 2654435761u; r ^= r >> 16;
            x = (float)(r & 0xFFFFu) * (1.0f / 65536.0f) - 0.45f;
        } else {
            x = u_ws[tid];
        }
        w[tid] = x;
    }
    if (tid == 0) { s_meff = m_max; s_done = 0; beta[0] = 0.f; }
    __syncthreads();
    if (wv == 0) {
        float a = w[lane] * w[lane];
        if (lane < 32) a += w[lane + 64] * w[lane + 64];
        #pragma unroll
        for (int o = 32; o; o >>= 1) a += __shfl_xor(a, o);
        if (lane == 0) s_scal[0] = sqrtf(a);
    }
    __syncthreads();
    if (tid < N) V[0][tid] = w[tid] / s_scal[0];
    __syncthreads();

    // ---------------- Lanczos (full-reorth form) ----------------
    for (int j = 0; j < m_max; ++j) {
        if (s_done) break;                       // uniform (read after sync)
        {   // w = Fs * V[j]
            const int i = tid >> 2, c = tid & 3;
            const float* qv  = &V[j][0];
            const float* row = &Fs[i * 97 + c * 24];
            float p = 0.f;
            #pragma unroll
            for (int k = 0; k < 24; ++k) p += row[k] * qv[c * 24 + k];
            p += __shfl_xor(p, 1);
            p += __shfl_xor(p, 2);
            if (c == 0) w[i] = p;
        }
        __syncthreads();
        // CGS pass 1 dots: dred[k] = <V[k], w>, k<=j  (alpha[j] = dred[j])
        for (int k = wv; k <= j; k += 6) {
            float a = V[k][lane] * w[lane];
            if (lane < 32) a += V[k][lane + 64] * w[lane + 64];
            #pragma unroll
            for (int o = 32; o; o >>= 1) a += __shfl_xor(a, o);
            if (lane == 0) dred[k] = a;
        }
        __syncthreads();
        if (tid == 0) alpha[j] = dred[j];
        if (j + 1 == m_max) break;               // uniform; alpha[j] recorded
        if (tid < N) {
            float x = w[tid];
            for (int k = 0; k <= j; ++k) x -= dred[k] * V[k][tid];
            w[tid] = x;
        }
        __syncthreads();
        // CGS pass 2 dots (rounding correction; also corrects alpha)
        for (int k = wv; k <= j; k += 6) {
            float a = V[k][lane] * w[lane];
            if (lane < 32) a += V[k][lane + 64] * w[lane + 64];
            #pragma unroll
            for (int o = 32; o; o >>= 1) a += __shfl_xor(a, o);
            if (lane == 0) dred[k] = a;
        }
        __syncthreads();
        if (tid == 0) alpha[j] += dred[j];
        if (tid < N) {
            float x = w[tid];
            for (int k = 0; k <= j; ++k) x -= dred[k] * V[k][tid];
            w[tid] = x;
        }
        __syncthreads();
        if (wv == 0) {   // beta[j+1] = ||w||
            float a = w[lane] * w[lane];
            if (lane < 32) a += w[lane + 64] * w[lane + 64];
            #pragma unroll
            for (int o = 32; o; o >>= 1) a += __shfl_xor(a, o);
            if (lane == 0) s_scal[0] = sqrtf(a);
        }
        __syncthreads();
        float b = s_scal[0];
        if (tid == 0) beta[j + 1] = b;
        if (b < 1e-5f) {                         // breakdown => invariant subspace
            if (tid == 0) { s_meff = j + 1; s_done = 1; }
        } else {
            if (tid < N) V[j + 1][tid] = w[tid] / b;
        }
        __syncthreads();
    }
    __syncthreads();
    const int m = s_meff;

    // ------------- smallest eigenvalue of tridiag via parallel bisection -----
    if (wv == 0) {
        float lo_l = 3e38f, hid = 3e38f;
        if (lane < m) {
            float bl = (lane > 0) ? fabsf(beta[lane]) : 0.f;
            float br = (lane + 1 < m) ? fabsf(beta[lane + 1]) : 0.f;
            lo_l = alpha[lane] - bl - br;
            hid  = alpha[lane];                  // lambda_min <= min diag
        }
        #pragma unroll
        for (int o = 32; o; o >>= 1) {
            lo_l = fminf(lo_l, __shfl_xor(lo_l, o));
            hid  = fminf(hid,  __shfl_xor(hid,  o));
        }
        float lo = lo_l - 1e-5f, hi = hid + 1e-5f;
        for (int round = 0; round < 4; ++round) {
            float x = lo + (hi - lo) * (float)(lane + 1) * (1.0f / 65.0f);
            int cnt = 0;
            float q = alpha[0] - x;
            if (q < 0.f) cnt++;
            for (int i = 1; i < m; ++i) {
                if (fabsf(q) < 1e-25f) q = (q < 0.f) ? -1e-25f : 1e-25f;
                float bi = beta[i];
                q = (alpha[i] - x) - bi * bi / q;
                if (q < 0.f) cnt++;
            }
            unsigned long long mask = __ballot(cnt >= 1);
            if (mask == 0ull) {
                lo = lo + (hi - lo) * (64.0f / 65.0f);
            } else {
                int f = __builtin_ctzll(mask);
                float xf  = lo + (hi - lo) * (float)(f + 1) * (1.0f / 65.0f);
                float xfm = lo + (hi - lo) * (float)(f)     * (1.0f / 65.0f);
                hi = xf; lo = xfm;
            }
        }
        if (lane == 0) s_scal[1] = 0.5f * (lo + hi);
    }
    __syncthreads();

    // ------------- tridiagonal inverse iteration (fp64 Thomas, thread 0) -----
    // Shift 1e-6 BELOW the bisection midpoint: T - lam stays positive definite
    // => pivots bounded away from 0 => no overflow (round-1 NaN fix).
    if (tid == 0) {
        if (m == 1) {
            wsml[0] = 1.0f;
        } else {
            double lam = (double)s_scal[1] - 1e-6;
            for (int pass = 0; pass < 2; ++pass) {
                double b0 = (double)alpha[0] - lam;
                if (fabs(b0) < 1e-18) b0 = (b0 < 0.0) ? -1e-18 : 1e-18;
                cp[0] = (double)beta[1] / b0;
                dp[0] = (pass ? (double)wsml[0] : 1.0) / b0;
                for (int i = 1; i < m; ++i) {
                    double ai = (double)beta[i];
                    double md = ((double)alpha[i] - lam) - ai * cp[i - 1];
                    if (fabs(md) < 1e-18) md = (md < 0.0) ? -1e-18 : 1e-18;
                    cp[i] = ((i + 1 < m) ? (double)beta[i + 1] : 0.0) / md;
                    double rhs = pass ? (double)wsml[i] : 1.0;
                    dp[i] = (rhs - ai * dp[i - 1]) / md;
                }
                for (int i = m - 2; i >= 0; --i) dp[i] -= cp[i] * dp[i + 1];
                double nn = 0.0;
                for (int i = 0; i < m; ++i) nn += dp[i] * dp[i];
                if (!(nn > 0.0) || isinf(nn)) {   // paranoia fallback
                    for (int i = 0; i < m; ++i) wsml[i] = (i == 0) ? 1.0f : 0.0f;
                } else {
                    double inv = 1.0 / sqrt(nn);
                    for (int i = 0; i < m; ++i) wsml[i] = (float)(dp[i] * inv);
                }
            }
        }
    }
    __syncthreads();

    // Ritz vector u = V^T wsml
    if (tid < N) {
        float acc = 0.f;
        for (int j = 0; j < m; ++j) acc += wsml[j] * V[j][tid];
        w[tid] = acc;
    }
    __syncthreads();
    if (wv == 0) {
        float a = w[lane] * w[lane];
        if (lane < 32) a += w[lane + 64] * w[lane + 64];
        #pragma unroll
        for (int o = 32; o; o >>= 1) a += __shfl_xor(a, o);
        if (lane == 0) s_scal[2] = sqrtf(a);
    }
    __syncthreads();
    if (tid < N) {
        float un = w[tid] / s_scal[2];
        w[tid] = un;
        u_ws[tid] = un;              // warm start for next SCF iteration
    }
    __syncthreads();
    // v = A @ u  (unnormalized Cocc column; D = v v^T)
    if (tid < N) {
        float acc = 0.f;
        for (int k = 0; k < N; ++k) acc += A[tid * N + k] * w[k];
        vn[tid] = acc;
        v_ws[tid] = acc;
    }
    __syncthreads();
    // energy rows: w[i] = sum_k (F+H)[i,k] * vn[k]
    {
        const int i = tid >> 2, c = tid & 3;
        float p = 0.f;
        const int base = i * N + c * 24;
        #pragma unroll
        for (int k = 0; k < 24; ++k) p += (F[base + k] + H[base + k]) * vn[c * 24 + k];
        p += __shfl_xor(p, 1);
        p += __shfl_xor(p, 2);
        if (c == 0) w[i] = p;
    }
    __syncthreads();
    if (wv == 0) {
        float e = vn[lane] * w[lane];
        if (lane < 32) e += vn[lane + 64] * w[lane + 64];
        #pragma unroll
        for (int o = 32; o; o >>= 1) e += __shfl_xor(e, o);
        if (lane == 0 && writeE) out[0] = e + Enuc[0];
    }
}

// ---------------------------------------------------------------------------
extern "C" void kernel_launch(void* const* d_in, const int* in_sizes, int n_in,
                              void* d_out, int out_size, void* d_ws, size_t ws_size,
                              hipStream_t stream)
{
    (void)in_sizes; (void)n_in; (void)out_size; (void)ws_size;
    // inputs: D (zeros, unused), H, A, G, Enuc
    const float* H    = (const float*)d_in[1];
    const float* A    = (const float*)d_in[2];
    const float* G    = (const float*)d_in[3];
    const float* Enuc = (const float*)d_in[4];
    float* out = (float*)d_out;
    float* ws  = (float*)d_ws;
    float* v  = ws + OFF_V;
    float* u  = ws + OFF_U;
    float* F  = ws + OFF_F;
    float* M1 = ws + OFF_M1;
    float* Fp = ws + OFF_FP;
    float* T  = ws + OFF_T;

    for (int it = 0; it < 20; ++it) {
        if (it > 0) {
            k_contract<<<NPAIR_SYM, 256, 0, stream>>>(G, v, T);
        }
        k_buildF<<<96, 256, 0, stream>>>(T, v, H, A, F, M1, it == 0 ? 1 : 0);
        k_AM<<<96, 128, 0, stream>>>(A, M1, Fp);
        k_eig<<<1, 384, 0, stream>>>(Fp, A, F, H, Enuc, v, u, out,
                                     it == 0 ? 1 : 0,
                                     it == 0 ? M_COLD : M_WARM,
                                     it == 19 ? 1 : 0);
    }
}

// Round 4
// 1358.514 us; speedup vs baseline: 2.8895x; 1.2587x over previous
//
#include <hip/hip_runtime.h>
#include <math.h>

#define N   96
#define N2  9216
#define NPAIR_SYM 4656     // 96*97/2 (p<=q) pair-blocks of G

#define M_COLD 32
#define M_WARM 12

// d_ws layout (float offsets)
#define OFF_V   0                  // 96: v = A@u (unnormalized Cocc column) -> density D = v v^T
#define OFF_U   128                // 96: u (normalized eigvec of Fp) for warm start
#define OFF_F   256                // 9216: F
#define OFF_M1  (OFF_F  + N2)      // 9216: M1 = F@A
#define OFF_FP  (OFF_M1 + N2)      // 9216: Fp = A@F@A
#define OFF_T   (OFF_FP + N2)      // 884736: T[p][q][r] = sum_s G[p,q,r,s] v_s

// ---------------------------------------------------------------------------
// T via pair symmetry G[p,q,r,s] = G[q,p,s,r]:
// one block per (p<=q): stage M = G[p,q,:,:] (36KB), then
//   T[p,q,r] = (M v)_r   and   T[q,p,s] = (M^T v)_s.
// Reads only 168MB of G per SCF iteration (vs 336MB), L3-cacheable.
// ---------------------------------------------------------------------------
__global__ __launch_bounds__(256)
void k_contract(const float* __restrict__ G, const float* __restrict__ v,
                float* __restrict__ T)
{
    __shared__ float Ms[N * 97];   // stride 97: conflict-free row AND col dots
    __shared__ float vs[N];
    const int tid = threadIdx.x;
    const int b   = blockIdx.x;
    // decode b -> (p,q), p<=q ; start(p) = p*96 - p*(p-1)/2
    int p = (int)((193.0 - sqrt(37249.0 - 8.0 * (double)b)) * 0.5);
    if (p > 95) p = 95;
    if (p < 0) p = 0;
    while (p * 96 - p * (p - 1) / 2 > b) --p;
    while ((p + 1) * 96 - (p + 1) * p / 2 <= b) ++p;
    const int q = p + (b - (p * 96 - p * (p - 1) / 2));

    if (tid < N) vs[tid] = v[tid];
    {   // stage M as float4 (96%4==0 so each float4 stays in one row)
        const float4* G4 = (const float4*)(G + (size_t)(p * N + q) * N2);
        #pragma unroll
        for (int k = tid; k < N2 / 4; k += 256) {
            float4 f = G4[k];
            int r = k / 24, s4 = k - r * 24;
            float* dst = &Ms[r * 97 + 4 * s4];
            dst[0] = f.x; dst[1] = f.y; dst[2] = f.z; dst[3] = f.w;
        }
    }
    __syncthreads();
    if (tid < N) {                 // row dot: T[p,q,tid] = sum_s M[tid][s] v[s]
        const float* row = &Ms[tid * 97];
        float acc = 0.f;
        #pragma unroll 8
        for (int s = 0; s < N; ++s) acc += row[s] * vs[s];
        T[(size_t)(p * N + q) * N + tid] = acc;
    } else if (tid < 2 * N && p != q) {  // col dot: T[q,p,s] = sum_r M[r][s] v[r]
        const int s = tid - N;
        float acc = 0.f;
        #pragma unroll 8
        for (int r = 0; r < N; ++r) acc += Ms[r * 97 + s] * vs[r];
        T[(size_t)(q * N + p) * N + s] = acc;
    }
}

// ---------------------------------------------------------------------------
// Block p: stage T[p] tile, J[p,:] = T[p,q,:]·v, K[p,:] = v·T[p,:,q],
// F[p,:] = H + 2J - K, M1[p,:] = F[p,:] @ A.
// ---------------------------------------------------------------------------
__global__ __launch_bounds__(256)
void k_buildF(const float* __restrict__ T, const float* __restrict__ v,
              const float* __restrict__ H, const float* __restrict__ A,
              float* __restrict__ F, float* __restrict__ M1, int zeroD)
{
    __shared__ float Ts[N * 97];
    __shared__ float vs[N];
    __shared__ float Frow[N];
    const int p = blockIdx.x, tid = threadIdx.x;
    if (!zeroD) {
        if (tid < N) vs[tid] = v[tid];
        for (int i = tid; i < N2; i += 256) {
            int q = i / N, r = i - q * N;
            Ts[q * 97 + r] = T[(size_t)p * N2 + i];
        }
    }
    __syncthreads();
    if (tid < N) {
        const int q = tid;
        float J = 0.f, K = 0.f;
        if (!zeroD) {
            for (int r = 0; r < N; ++r) {
                J += Ts[q * 97 + r] * vs[r];
                K += vs[r] * Ts[r * 97 + q];
            }
        }
        float f = H[p * N + q] + 2.0f * J - K;
        Frow[q] = f;
        F[p * N + q] = f;
    }
    __syncthreads();
    if (tid < N) {
        const int q = tid;
        float acc = 0.f;
        for (int k = 0; k < N; ++k) acc += Frow[k] * A[k * N + q];
        M1[p * N + q] = acc;
    }
}

// Fp[p,:] = A[p,:] @ M1
__global__ __launch_bounds__(128)
void k_AM(const float* __restrict__ A, const float* __restrict__ M1,
          float* __restrict__ Fp)
{
    __shared__ float Ar[N];
    const int p = blockIdx.x, tid = threadIdx.x;
    if (tid < N) Ar[tid] = A[p * N + tid];
    __syncthreads();
    if (tid < N) {
        float acc = 0.f;
        for (int k = 0; k < N; ++k) acc += Ar[k] * M1[k * N + tid];
        Fp[p * N + tid] = acc;
    }
}

// ---------------------------------------------------------------------------
// Single-block eigensolver, latency-optimized: 3 barriers per Lanczos step.
//   phase A (all 6 waves): w = Fs V[j]                    -> barrier
//   phase B (all waves):   dred[k] = <V[k],w>, alpha[j]   -> barrier
//   phase C (wave 0 only): w -= sum dred[k] V[k]; beta = ||w||;
//                          V[j+1] = w/beta   (wave-synchronous, no handoff)
//                                                          -> barrier
// Single CGS pass (orthogonality ~1e-5, ample for the 4.3e-2 E-threshold).
// Then bisection (lowest tridiag eigval) + fp64 inverse iteration + Ritz,
// v = A@u, E = v^T (F+H) v + Enuc.
// ---------------------------------------------------------------------------
__global__ __launch_bounds__(384)
void k_eig(const float* __restrict__ Fp, const float* __restrict__ A,
           const float* __restrict__ F, const float* __restrict__ H,
           const float* __restrict__ Enuc,
           float* __restrict__ v_ws, float* __restrict__ u_ws,
           float* __restrict__ out, int cold, int m_max, int writeE)
{
    __shared__ float  Fs[N * 97];          // 37248 B
    __shared__ float  V[M_COLD][N];        // 12288 B
    __shared__ float  w[N];
    __shared__ float  vn[N];
    __shared__ float  alpha[M_COLD + 1];
    __shared__ float  beta[M_COLD + 1];
    __shared__ float  dred[M_COLD];
    __shared__ float  wsml[M_COLD];
    __shared__ double cp[M_COLD];
    __shared__ double dp[M_COLD];
    __shared__ float  s_scal[4];
    __shared__ int    s_meff, s_done;

    const int tid  = threadIdx.x;
    const int lane = tid & 63;
    const int wv   = tid >> 6;

    {   // stage Fp -> Fs as float4 (rows of 96 = 24 float4)
        const float4* Fp4 = (const float4*)Fp;
        #pragma unroll
        for (int k = tid; k < N2 / 4; k += 384) {
            float4 f = Fp4[k];
            int r = k / 24, c4 = (k - r * 24) * 4;
            float* dst = &Fs[r * 97 + c4];
            dst[0] = f.x; dst[1] = f.y; dst[2] = f.z; dst[3] = f.w;
        }
    }
    if (tid < N) {
        float x;
        if (cold) {   // deterministic generic start vector
            unsigned r = (unsigned)tid * 1103515245u + 12345u;
            r ^= r >> 13; r *= 2654435761u; r ^= r >> 16;
            x = (float)(r & 0xFFFFu) * (1.0f / 65536.0f) - 0.45f;
        } else {
            x = u_ws[tid];
        }
        w[tid] = x;
    }
    if (tid == 0) { s_meff = m_max; s_done = 0; beta[0] = 0.f; }
    __syncthreads();
    if (wv == 0) {   // normalize w -> V[0], wave-synchronous
        float x0 = w[lane];
        float x1 = (lane < 32) ? w[lane + 64] : 0.f;
        float a = x0 * x0 + x1 * x1;
        #pragma unroll
        for (int o = 32; o; o >>= 1) a += __shfl_xor(a, o);
        float ib = 1.0f / sqrtf(a);
        V[0][lane] = x0 * ib;
        if (lane < 32) V[0][lane + 64] = x1 * ib;
    }
    __syncthreads();

    // ---------------- Lanczos: 3 barriers/step ----------------
    for (int j = 0; j < m_max; ++j) {
        if (s_done) break;                       // uniform (read after barrier)
        {   // A: w = Fs * V[j]   (96 rows x 4-lane splits)
            const int i = tid >> 2, c = tid & 3;
            const float* qv  = &V[j][0];
            const float* row = &Fs[i * 97 + c * 24];
            float p = 0.f;
            #pragma unroll
            for (int k = 0; k < 24; ++k) p += row[k] * qv[c * 24 + k];
            p += __shfl_xor(p, 1);
            p += __shfl_xor(p, 2);
            if (c == 0) w[i] = p;
        }
        __syncthreads();
        // B: dred[k] = <V[k], w> for k<=j ; alpha[j] = dred[j]
        for (int k = wv; k <= j; k += 6) {
            float a = V[k][lane] * w[lane];
            if (lane < 32) a += V[k][lane + 64] * w[lane + 64];
            #pragma unroll
            for (int o = 32; o; o >>= 1) a += __shfl_xor(a, o);
            if (lane == 0) { dred[k] = a; if (k == j) alpha[j] = a; }
        }
        __syncthreads();
        if (j + 1 == m_max) break;               // uniform; alpha[j] recorded
        // C: wave 0 alone: orthogonalize, norm, write V[j+1]
        if (wv == 0) {
            float x0 = w[lane];
            float x1 = (lane < 32) ? w[lane + 64] : 0.f;
            for (int k = 0; k <= j; ++k) {
                float d = dred[k];
                x0 -= d * V[k][lane];
                if (lane < 32) x1 -= d * V[k][lane + 64];
            }
            float a = x0 * x0 + x1 * x1;
            #pragma unroll
            for (int o = 32; o; o >>= 1) a += __shfl_xor(a, o);
            float b = sqrtf(a);
            if (lane == 0) beta[j + 1] = b;
            if (b < 1e-5f) {                     // breakdown => converged subspace
                if (lane == 0) { s_meff = j + 1; s_done = 1; }
            } else {
                float ib = 1.0f / b;
                V[j + 1][lane] = x0 * ib;
                if (lane < 32) V[j + 1][lane + 64] = x1 * ib;
            }
        }
        __syncthreads();
    }
    __syncthreads();
    const int m = s_meff;

    // ------------- smallest eigenvalue of tridiag via parallel bisection -----
    if (wv == 0) {
        float lo_l = 3e38f, hid = 3e38f;
        if (lane < m) {
            float bl = (lane > 0) ? fabsf(beta[lane]) : 0.f;
            float br = (lane + 1 < m) ? fabsf(beta[lane + 1]) : 0.f;
            lo_l = alpha[lane] - bl - br;
            hid  = alpha[lane];                  // lambda_min <= min diag
        }
        #pragma unroll
        for (int o = 32; o; o >>= 1) {
            lo_l = fminf(lo_l, __shfl_xor(lo_l, o));
            hid  = fminf(hid,  __shfl_xor(hid,  o));
        }
        float lo = lo_l - 1e-5f, hi = hid + 1e-5f;
        for (int round = 0; round < 4; ++round) {
            float x = lo + (hi - lo) * (float)(lane + 1) * (1.0f / 65.0f);
            int cnt = 0;
            float q = alpha[0] - x;
            if (q < 0.f) cnt++;
            for (int i = 1; i < m; ++i) {
                if (fabsf(q) < 1e-25f) q = (q < 0.f) ? -1e-25f : 1e-25f;
                float bi = beta[i];
                q = (alpha[i] - x) - bi * bi / q;
                if (q < 0.f) cnt++;
            }
            unsigned long long mask = __ballot(cnt >= 1);
            if (mask == 0ull) {
                lo = lo + (hi - lo) * (64.0f / 65.0f);
            } else {
                int f = __builtin_ctzll(mask);
                float xf  = lo + (hi - lo) * (float)(f + 1) * (1.0f / 65.0f);
                float xfm = lo + (hi - lo) * (float)(f)     * (1.0f / 65.0f);
                hi = xf; lo = xfm;
            }
        }
        if (lane == 0) s_scal[1] = 0.5f * (lo + hi);
    }
    __syncthreads();

    // ------------- tridiagonal inverse iteration (fp64 Thomas, thread 0) -----
    // Shift 1e-6 BELOW the bisection midpoint: T - lam stays positive definite
    // => pivots bounded away from 0 => no overflow.
    if (tid == 0) {
        if (m == 1) {
            wsml[0] = 1.0f;
        } else {
            double lam = (double)s_scal[1] - 1e-6;
            for (int pass = 0; pass < 2; ++pass) {
                double b0 = (double)alpha[0] - lam;
                if (fabs(b0) < 1e-18) b0 = (b0 < 0.0) ? -1e-18 : 1e-18;
                cp[0] = (double)beta[1] / b0;
                dp[0] = (pass ? (double)wsml[0] : 1.0) / b0;
                for (int i = 1; i < m; ++i) {
                    double ai = (double)beta[i];
                    double md = ((double)alpha[i] - lam) - ai * cp[i - 1];
                    if (fabs(md) < 1e-18) md = (md < 0.0) ? -1e-18 : 1e-18;
                    cp[i] = ((i + 1 < m) ? (double)beta[i + 1] : 0.0) / md;
                    double rhs = pass ? (double)wsml[i] : 1.0;
                    dp[i] = (rhs - ai * dp[i - 1]) / md;
                }
                for (int i = m - 2; i >= 0; --i) dp[i] -= cp[i] * dp[i + 1];
                double nn = 0.0;
                for (int i = 0; i < m; ++i) nn += dp[i] * dp[i];
                if (!(nn > 0.0) || isinf(nn)) {   // paranoia fallback
                    for (int i = 0; i < m; ++i) wsml[i] = (i == 0) ? 1.0f : 0.0f;
                } else {
                    double inv = 1.0 / sqrt(nn);
                    for (int i = 0; i < m; ++i) wsml[i] = (float)(dp[i] * inv);
                }
            }
        }
    }
    __syncthreads();

    // Ritz vector u = V^T wsml
    if (tid < N) {
        float acc = 0.f;
        for (int j = 0; j < m; ++j) acc += wsml[j] * V[j][tid];
        w[tid] = acc;
    }
    __syncthreads();
    if (wv == 0) {
        float a = w[lane] * w[lane];
        if (lane < 32) a += w[lane + 64] * w[lane + 64];
        #pragma unroll
        for (int o = 32; o; o >>= 1) a += __shfl_xor(a, o);
        if (lane == 0) s_scal[2] = sqrtf(a);
    }
    __syncthreads();
    if (tid < N) {
        float un = w[tid] / s_scal[2];
        w[tid] = un;
        u_ws[tid] = un;              // warm start for next SCF iteration
    }
    __syncthreads();
    // v = A @ u  (unnormalized Cocc column; D = v v^T)
    if (tid < N) {
        float acc = 0.f;
        for (int k = 0; k < N; ++k) acc += A[tid * N + k] * w[k];
        vn[tid] = acc;
        v_ws[tid] = acc;
    }
    __syncthreads();
    // energy rows: w[i] = sum_k (F+H)[i,k] * vn[k]
    {
        const int i = tid >> 2, c = tid & 3;
        float p = 0.f;
        const int base = i * N + c * 24;
        #pragma unroll
        for (int k = 0; k < 24; ++k) p += (F[base + k] + H[base + k]) * vn[c * 24 + k];
        p += __shfl_xor(p, 1);
        p += __shfl_xor(p, 2);
        if (c == 0) w[i] = p;
    }
    __syncthreads();
    if (wv == 0) {
        float e = vn[lane] * w[lane];
        if (lane < 32) e += vn[lane + 64] * w[lane + 64];
        #pragma unroll
        for (int o = 32; o; o >>= 1) e += __shfl_xor(e, o);
        if (lane == 0 && writeE) out[0] = e + Enuc[0];
    }
}

// ---------------------------------------------------------------------------
extern "C" void kernel_launch(void* const* d_in, const int* in_sizes, int n_in,
                              void* d_out, int out_size, void* d_ws, size_t ws_size,
                              hipStream_t stream)
{
    (void)in_sizes; (void)n_in; (void)out_size; (void)ws_size;
    // inputs: D (zeros, unused), H, A, G, Enuc
    const float* H    = (const float*)d_in[1];
    const float* A    = (const float*)d_in[2];
    const float* G    = (const float*)d_in[3];
    const float* Enuc = (const float*)d_in[4];
    float* out = (float*)d_out;
    float* ws  = (float*)d_ws;
    float* v  = ws + OFF_V;
    float* u  = ws + OFF_U;
    float* F  = ws + OFF_F;
    float* M1 = ws + OFF_M1;
    float* Fp = ws + OFF_FP;
    float* T  = ws + OFF_T;

    for (int it = 0; it < 20; ++it) {
        if (it > 0) {
            k_contract<<<NPAIR_SYM, 256, 0, stream>>>(G, v, T);
        }
        k_buildF<<<96, 256, 0, stream>>>(T, v, H, A, F, M1, it == 0 ? 1 : 0);
        k_AM<<<96, 128, 0, stream>>>(A, M1, Fp);
        k_eig<<<1, 384, 0, stream>>>(Fp, A, F, H, Enuc, v, u, out,
                                     it == 0 ? 1 : 0,
                                     it == 0 ? M_COLD : M_WARM,
                                     it == 19 ? 1 : 0);
    }
}

// Round 5
// 1176.924 us; speedup vs baseline: 3.3353x; 1.1543x over previous
//
#include <hip/hip_runtime.h>
#include <math.h>

#define N   96
#define N2  9216
#define NPAIR_SYM 4656     // 96*97/2 (p<=q) pair-blocks of G

#define M_COLD 24
#define M_WARM 8

// d_ws layout (float offsets)
#define OFF_V   0                  // 96: v = A@u (Cocc column; D = v v^T)
#define OFF_U   128                // 96: u (eigvec of Fp) warm start
#define OFF_F   256                // 9216: F
#define OFF_M1  (OFF_F  + N2)      // 9216: M1 = F@A
#define OFF_J   (OFF_M1 + N2)      // 9216: J
#define OFF_K   (OFF_J  + N2)      // 9216: K (atomic-accumulated)
#define OFF_GB  (OFF_K  + N2)      // bf16 G-half: 4656*9216 ushorts
#define NEED_BF16_BYTES ((size_t)OFF_GB * 4 + (size_t)NPAIR_SYM * N2 * 2)

__device__ __forceinline__ unsigned short f2bf(float x) {
    unsigned u = __float_as_uint(x);
    unsigned r = (u + 0x7FFFu + ((u >> 16) & 1u)) >> 16;
    return (unsigned short)r;
}
__device__ __forceinline__ float bf2f(unsigned h) {
    return __uint_as_float(h << 16);
}

// ---------------------------------------------------------------------------
// Per pair-block (p<=q), M = G[p,q,:,:]:
//   Trow = M v, Tcol = M^T v
//   J[p,q] = Trow.v ; J[q,p] = Tcol.v            (exclusive writes)
//   K[p,:] += v_q * Trow ; K[q,:] += v_p * Tcol  (atomicAdd)
// MODE 0: read fp32 G. MODE 1: read fp32 G, also write bf16 copy Gb.
// MODE 2: read bf16 Gb (84 MB/iter, L3-resident).
// ---------------------------------------------------------------------------
template <int MODE>
__global__ __launch_bounds__(256)
void k_contract(const float* __restrict__ G, unsigned short* __restrict__ Gb,
                const float* __restrict__ v,
                float* __restrict__ J, float* __restrict__ K)
{
    __shared__ float Ms[N * 97];   // stride 97: conflict-free row AND col dots
    __shared__ float vs[N];
    __shared__ float rsh[N];
    __shared__ float csh[N];
    const int tid = threadIdx.x;
    const int b   = blockIdx.x;
    // decode b -> (p,q), p<=q
    int p = (int)((193.0 - sqrt(37249.0 - 8.0 * (double)b)) * 0.5);
    if (p > 95) p = 95;
    if (p < 0) p = 0;
    while (p * 96 - p * (p - 1) / 2 > b) --p;
    while ((p + 1) * 96 - (p + 1) * p / 2 <= b) ++p;
    const int q = p + (b - (p * 96 - p * (p - 1) / 2));
    const int pr = b;

    if (tid < N) vs[tid] = v[tid];
    if (MODE == 2) {
        const uint4* Gb4 = (const uint4*)(Gb + (size_t)pr * N2);
        for (int i = tid; i < N2 / 8; i += 256) {   // 8 bf16 per uint4
            uint4 u = Gb4[i];
            int r = i / 12, s0 = (i - r * 12) * 8;
            float* dst = &Ms[r * 97 + s0];
            dst[0] = bf2f(u.x & 0xFFFFu); dst[1] = bf2f(u.x >> 16);
            dst[2] = bf2f(u.y & 0xFFFFu); dst[3] = bf2f(u.y >> 16);
            dst[4] = bf2f(u.z & 0xFFFFu); dst[5] = bf2f(u.z >> 16);
            dst[6] = bf2f(u.w & 0xFFFFu); dst[7] = bf2f(u.w >> 16);
        }
    } else {
        const float4* G4 = (const float4*)(G + (size_t)(p * N + q) * N2);
        uint2* Gb2 = (MODE == 1) ? (uint2*)(Gb + (size_t)pr * N2) : nullptr;
        for (int k = tid; k < N2 / 4; k += 256) {
            float4 f = G4[k];
            int r = k / 24, s4 = (k - r * 24) * 4;
            float* dst = &Ms[r * 97 + s4];
            dst[0] = f.x; dst[1] = f.y; dst[2] = f.z; dst[3] = f.w;
            if (MODE == 1) {
                uint2 o;
                o.x = (unsigned)f2bf(f.x) | ((unsigned)f2bf(f.y) << 16);
                o.y = (unsigned)f2bf(f.z) | ((unsigned)f2bf(f.w) << 16);
                Gb2[k] = o;
            }
        }
    }
    __syncthreads();
    if (tid < N) {                 // row dot r=tid: Trow[r] = sum_s M[r][s] v[s]
        const float* row = &Ms[tid * 97];
        float acc = 0.f;
        #pragma unroll 8
        for (int s = 0; s < N; ++s) acc += row[s] * vs[s];
        atomicAdd(&K[p * N + tid], vs[q] * acc);
        rsh[tid] = acc * vs[tid];
    } else if (tid < 2 * N && p != q) {  // col dot s: Tcol[s] = sum_r M[r][s] v[r]
        const int s = tid - N;
        float acc = 0.f;
        #pragma unroll 8
        for (int r = 0; r < N; ++r) acc += Ms[r * 97 + s] * vs[r];
        atomicAdd(&K[q * N + s], vs[p] * acc);
        csh[s] = acc * vs[s];
    }
    __syncthreads();
    const int lane = tid & 63, wv = tid >> 6;
    if (wv == 0) {                 // J[p,q] = Trow.v
        float a = rsh[lane];
        if (lane < 32) a += rsh[lane + 64];
        #pragma unroll
        for (int o = 32; o; o >>= 1) a += __shfl_xor(a, o);
        if (lane == 0) J[p * N + q] = a;
    } else if (wv == 1 && p != q) { // J[q,p] = Tcol.v
        float a = csh[lane];
        if (lane < 32) a += csh[lane + 64];
        #pragma unroll
        for (int o = 32; o; o >>= 1) a += __shfl_xor(a, o);
        if (lane == 0) J[q * N + p] = a;
    }
}

// ---------------------------------------------------------------------------
// Block p: F[p,:] = H + 2J - K ; M1[p,:] = F[p,:] @ A.
// ---------------------------------------------------------------------------
__global__ __launch_bounds__(128)
void k_buildF(const float* __restrict__ J, const float* __restrict__ K,
              const float* __restrict__ H, const float* __restrict__ A,
              float* __restrict__ F, float* __restrict__ M1, int zeroD)
{
    __shared__ float As[N * 97];
    __shared__ float Frow[N];
    const int p = blockIdx.x, tid = threadIdx.x;
    {   // stage A (stride 97 -> conflict-free column reads)
        const float4* A4 = (const float4*)A;
        for (int k = tid; k < N2 / 4; k += 128) {
            float4 f = A4[k];
            int r = k / 24, c4 = (k - r * 24) * 4;
            float* dst = &As[r * 97 + c4];
            dst[0] = f.x; dst[1] = f.y; dst[2] = f.z; dst[3] = f.w;
        }
    }
    if (tid < N) {
        float f = H[p * N + tid];
        if (!zeroD) f += 2.0f * J[p * N + tid] - K[p * N + tid];
        Frow[tid] = f;
        F[p * N + tid] = f;
    }
    __syncthreads();
    if (tid < N) {
        float acc = 0.f;
        for (int k = 0; k < N; ++k) acc += Frow[k] * As[k * 97 + tid];
        M1[p * N + tid] = acc;
    }
}

// ---------------------------------------------------------------------------
// Single-block eigensolver. Fp = A@F@A applied as Fp x = A(M1 x) -- no Fp
// materialization (k_AM eliminated). 4 barriers per Lanczos step:
//   y = M1 V[j] | w = A y | dred[k]=<V[k],w>, alpha[j] | wave0: orth+norm+V[j+1]
// Then bisection + fp64 inverse iteration + Ritz, v = A@u,
// E = v^T (F+H) v + Enuc. Also zeroes J/K for next iteration's contract.
// ---------------------------------------------------------------------------
__global__ __launch_bounds__(384)
void k_eig(const float* __restrict__ M1, const float* __restrict__ A,
           const float* __restrict__ F, const float* __restrict__ H,
           const float* __restrict__ Enuc,
           float* __restrict__ v_ws, float* __restrict__ u_ws,
           float* __restrict__ jk,   // J,K contiguous: 2*N2 floats to zero
           float* __restrict__ out, int cold, int m_max, int writeE)
{
    __shared__ float  Ms[N * 97];          // M1
    __shared__ float  As[N * 97];          // A
    __shared__ float  V[M_COLD][N];
    __shared__ float  w[N];
    __shared__ float  ysh[N];
    __shared__ float  vn[N];
    __shared__ float  alpha[M_COLD + 1];
    __shared__ float  beta[M_COLD + 1];
    __shared__ float  dred[M_COLD];
    __shared__ float  wsml[M_COLD];
    __shared__ double cp[M_COLD];
    __shared__ double dp[M_COLD];
    __shared__ float  s_scal[4];
    __shared__ int    s_meff, s_done;

    const int tid  = threadIdx.x;
    const int lane = tid & 63;
    const int wv   = tid >> 6;

    // zero J/K for next SCF iteration's k_contract (consumed already by buildF)
    for (int i = tid; i < 2 * N2; i += 384) jk[i] = 0.f;

    {   // stage M1 and A (stride 97)
        const float4* M14 = (const float4*)M1;
        const float4* A4  = (const float4*)A;
        for (int k = tid; k < N2 / 4; k += 384) {
            int r = k / 24, c4 = (k - r * 24) * 4;
            float4 f = M14[k];
            float* d = &Ms[r * 97 + c4];
            d[0] = f.x; d[1] = f.y; d[2] = f.z; d[3] = f.w;
            float4 g = A4[k];
            float* e = &As[r * 97 + c4];
            e[0] = g.x; e[1] = g.y; e[2] = g.z; e[3] = g.w;
        }
    }
    if (tid < N) {
        float x;
        if (cold) {   // deterministic generic start vector
            unsigned r = (unsigned)tid * 1103515245u + 12345u;
            r ^= r >> 13; r *= 2654435761u; r ^= r >> 16;
            x = (float)(r & 0xFFFFu) * (1.0f / 65536.0f) - 0.45f;
        } else {
            x = u_ws[tid];
        }
        w[tid] = x;
    }
    if (tid == 0) { s_meff = m_max; s_done = 0; beta[0] = 0.f; }
    __syncthreads();
    if (wv == 0) {   // normalize w -> V[0]
        float x0 = w[lane];
        float x1 = (lane < 32) ? w[lane + 64] : 0.f;
        float a = x0 * x0 + x1 * x1;
        #pragma unroll
        for (int o = 32; o; o >>= 1) a += __shfl_xor(a, o);
        float ib = 1.0f / sqrtf(a);
        V[0][lane] = x0 * ib;
        if (lane < 32) V[0][lane + 64] = x1 * ib;
    }
    __syncthreads();

    // ---------------- Lanczos: Fp x = A (M1 x) ----------------
    for (int j = 0; j < m_max; ++j) {
        if (s_done) break;
        const int i = tid >> 2, c = tid & 3;
        {   // y = Ms * V[j]
            const float* qv  = &V[j][0];
            const float* row = &Ms[i * 97 + c * 24];
            float p = 0.f;
            #pragma unroll
            for (int k = 0; k < 24; ++k) p += row[k] * qv[c * 24 + k];
            p += __shfl_xor(p, 1);
            p += __shfl_xor(p, 2);
            if (c == 0) ysh[i] = p;
        }
        __syncthreads();
        {   // w = As * y
            const float* row = &As[i * 97 + c * 24];
            float p = 0.f;
            #pragma unroll
            for (int k = 0; k < 24; ++k) p += row[k] * ysh[c * 24 + k];
            p += __shfl_xor(p, 1);
            p += __shfl_xor(p, 2);
            if (c == 0) w[i] = p;
        }
        __syncthreads();
        // dred[k] = <V[k], w>, alpha[j] = dred[j]
        for (int k = wv; k <= j; k += 6) {
            float a = V[k][lane] * w[lane];
            if (lane < 32) a += V[k][lane + 64] * w[lane + 64];
            #pragma unroll
            for (int o = 32; o; o >>= 1) a += __shfl_xor(a, o);
            if (lane == 0) { dred[k] = a; if (k == j) alpha[j] = a; }
        }
        __syncthreads();
        if (j + 1 == m_max) break;
        if (wv == 0) {   // orthogonalize, norm, V[j+1]
            float x0 = w[lane];
            float x1 = (lane < 32) ? w[lane + 64] : 0.f;
            for (int k = 0; k <= j; ++k) {
                float d = dred[k];
                x0 -= d * V[k][lane];
                if (lane < 32) x1 -= d * V[k][lane + 64];
            }
            float a = x0 * x0 + x1 * x1;
            #pragma unroll
            for (int o = 32; o; o >>= 1) a += __shfl_xor(a, o);
            float b = sqrtf(a);
            if (lane == 0) beta[j + 1] = b;
            if (b < 1e-5f) {
                if (lane == 0) { s_meff = j + 1; s_done = 1; }
            } else {
                float ib = 1.0f / b;
                V[j + 1][lane] = x0 * ib;
                if (lane < 32) V[j + 1][lane + 64] = x1 * ib;
            }
        }
        __syncthreads();
    }
    __syncthreads();
    const int m = s_meff;

    // ------------- smallest tridiag eigenvalue via 64-lane bisection ---------
    if (wv == 0) {
        float lo_l = 3e38f, hid = 3e38f;
        if (lane < m) {
            float bl = (lane > 0) ? fabsf(beta[lane]) : 0.f;
            float br = (lane + 1 < m) ? fabsf(beta[lane + 1]) : 0.f;
            lo_l = alpha[lane] - bl - br;
            hid  = alpha[lane];
        }
        #pragma unroll
        for (int o = 32; o; o >>= 1) {
            lo_l = fminf(lo_l, __shfl_xor(lo_l, o));
            hid  = fminf(hid,  __shfl_xor(hid,  o));
        }
        float lo = lo_l - 1e-5f, hi = hid + 1e-5f;
        for (int round = 0; round < 4; ++round) {
            float x = lo + (hi - lo) * (float)(lane + 1) * (1.0f / 65.0f);
            int cnt = 0;
            float qq = alpha[0] - x;
            if (qq < 0.f) cnt++;
            for (int i2 = 1; i2 < m; ++i2) {
                if (fabsf(qq) < 1e-25f) qq = (qq < 0.f) ? -1e-25f : 1e-25f;
                float bi = beta[i2];
                qq = (alpha[i2] - x) - bi * bi / qq;
                if (qq < 0.f) cnt++;
            }
            unsigned long long mask = __ballot(cnt >= 1);
            if (mask == 0ull) {
                lo = lo + (hi - lo) * (64.0f / 65.0f);
            } else {
                int f = __builtin_ctzll(mask);
                float xf  = lo + (hi - lo) * (float)(f + 1) * (1.0f / 65.0f);
                float xfm = lo + (hi - lo) * (float)(f)     * (1.0f / 65.0f);
                hi = xf; lo = xfm;
            }
        }
        if (lane == 0) s_scal[1] = 0.5f * (lo + hi);
    }
    __syncthreads();

    // ------------- fp64 inverse iteration, shift 1e-6 below lam_min ----------
    if (tid == 0) {
        if (m == 1) {
            wsml[0] = 1.0f;
        } else {
            double lam = (double)s_scal[1] - 1e-6;
            for (int pass = 0; pass < 2; ++pass) {
                double b0 = (double)alpha[0] - lam;
                if (fabs(b0) < 1e-18) b0 = (b0 < 0.0) ? -1e-18 : 1e-18;
                cp[0] = (double)beta[1] / b0;
                dp[0] = (pass ? (double)wsml[0] : 1.0) / b0;
                for (int i2 = 1; i2 < m; ++i2) {
                    double ai = (double)beta[i2];
                    double md = ((double)alpha[i2] - lam) - ai * cp[i2 - 1];
                    if (fabs(md) < 1e-18) md = (md < 0.0) ? -1e-18 : 1e-18;
                    cp[i2] = ((i2 + 1 < m) ? (double)beta[i2 + 1] : 0.0) / md;
                    double rhs = pass ? (double)wsml[i2] : 1.0;
                    dp[i2] = (rhs - ai * dp[i2 - 1]) / md;
                }
                for (int i2 = m - 2; i2 >= 0; --i2) dp[i2] -= cp[i2] * dp[i2 + 1];
                double nn = 0.0;
                for (int i2 = 0; i2 < m; ++i2) nn += dp[i2] * dp[i2];
                if (!(nn > 0.0) || isinf(nn)) {
                    for (int i2 = 0; i2 < m; ++i2) wsml[i2] = (i2 == 0) ? 1.0f : 0.0f;
                } else {
                    double inv = 1.0 / sqrt(nn);
                    for (int i2 = 0; i2 < m; ++i2) wsml[i2] = (float)(dp[i2] * inv);
                }
            }
        }
    }
    __syncthreads();

    // Ritz vector u = V^T wsml
    if (tid < N) {
        float acc = 0.f;
        for (int j = 0; j < m; ++j) acc += wsml[j] * V[j][tid];
        w[tid] = acc;
    }
    __syncthreads();
    if (wv == 0) {
        float a = w[lane] * w[lane];
        if (lane < 32) a += w[lane + 64] * w[lane + 64];
        #pragma unroll
        for (int o = 32; o; o >>= 1) a += __shfl_xor(a, o);
        if (lane == 0) s_scal[2] = sqrtf(a);
    }
    __syncthreads();
    if (tid < N) {
        float un = w[tid] / s_scal[2];
        w[tid] = un;
        u_ws[tid] = un;              // warm start for next SCF iteration
    }
    __syncthreads();
    // v = A @ u  (use staged As; row access)
    if (tid < N) {
        const float* row = &As[tid * 97];
        float acc = 0.f;
        for (int k = 0; k < N; ++k) acc += row[k] * w[k];
        vn[tid] = acc;
        v_ws[tid] = acc;
    }
    __syncthreads();
    // energy rows: w[i] = sum_k (F+H)[i,k] * vn[k]
    {
        const int i = tid >> 2, c = tid & 3;
        float p = 0.f;
        const int base = i * N + c * 24;
        #pragma unroll
        for (int k = 0; k < 24; ++k) p += (F[base + k] + H[base + k]) * vn[c * 24 + k];
        p += __shfl_xor(p, 1);
        p += __shfl_xor(p, 2);
        if (c == 0) w[i] = p;
    }
    __syncthreads();
    if (wv == 0) {
        float e = vn[lane] * w[lane];
        if (lane < 32) e += vn[lane + 64] * w[lane + 64];
        #pragma unroll
        for (int o = 32; o; o >>= 1) e += __shfl_xor(e, o);
        if (lane == 0 && writeE) out[0] = e + Enuc[0];
    }
}

// ---------------------------------------------------------------------------
extern "C" void kernel_launch(void* const* d_in, const int* in_sizes, int n_in,
                              void* d_out, int out_size, void* d_ws, size_t ws_size,
                              hipStream_t stream)
{
    (void)in_sizes; (void)n_in; (void)out_size;
    // inputs: D (zeros, unused), H, A, G, Enuc
    const float* H    = (const float*)d_in[1];
    const float* A    = (const float*)d_in[2];
    const float* G    = (const float*)d_in[3];
    const float* Enuc = (const float*)d_in[4];
    float* out = (float*)d_out;
    float* ws  = (float*)d_ws;
    float* v  = ws + OFF_V;
    float* u  = ws + OFF_U;
    float* F  = ws + OFF_F;
    float* M1 = ws + OFF_M1;
    float* J  = ws + OFF_J;
    float* K  = ws + OFF_K;
    unsigned short* Gb = (unsigned short*)(ws + OFF_GB);
    const bool bf16ok = ws_size >= NEED_BF16_BYTES;

    for (int it = 0; it < 20; ++it) {
        if (it > 0) {
            if (!bf16ok)
                k_contract<0><<<NPAIR_SYM, 256, 0, stream>>>(G, Gb, v, J, K);
            else if (it == 1)
                k_contract<1><<<NPAIR_SYM, 256, 0, stream>>>(G, Gb, v, J, K);
            else
                k_contract<2><<<NPAIR_SYM, 256, 0, stream>>>(G, Gb, v, J, K);
        }
        k_buildF<<<96, 128, 0, stream>>>(J, K, H, A, F, M1, it == 0 ? 1 : 0);
        k_eig<<<1, 384, 0, stream>>>(M1, A, F, H, Enuc, v, u, J, out,
                                     it == 0 ? 1 : 0,
                                     it == 0 ? M_COLD : M_WARM,
                                     it == 19 ? 1 : 0);
    }
}

// Round 6
// 818.180 us; speedup vs baseline: 4.7977x; 1.4385x over previous
//
#include <hip/hip_runtime.h>
#include <math.h>

#define N   96
#define N2  9216
#define NPAIR_SYM 4656     // 96*97/2 (p<=q) pair-blocks of G

#define M_COLD 24
#define M_WARM 8
#define CONV_TOL 4e-6f

// d_ws layout (float offsets)
#define OFF_V    0                 // 96: v = A@u (Cocc column; D = v v^T)
#define OFF_CONV 112               // 1 int: SCF converged flag
#define OFF_U    128               // 96: u (eigvec of Fp) warm start
#define OFF_F    256               // 9216: F
#define OFF_M1   (OFF_F  + N2)     // 9216: M1 = F@A
#define OFF_J    (OFF_M1 + N2)     // 9216: J
#define OFF_K    (OFF_J  + N2)     // 9216: K (atomic-accumulated)
#define OFF_GB   (OFF_K  + N2)     // bf16 G-half: 4656*9216 ushorts
#define NEED_BF16_BYTES ((size_t)OFF_GB * 4 + (size_t)NPAIR_SYM * N2 * 2)

__device__ __forceinline__ unsigned short f2bf(float x) {
    unsigned u = __float_as_uint(x);
    unsigned r = (u + 0x7FFFu + ((u >> 16) & 1u)) >> 16;
    return (unsigned short)r;
}
__device__ __forceinline__ float bf2f(unsigned h) {
    return __uint_as_float(h << 16);
}

// ---------------------------------------------------------------------------
// Per pair-block (p<=q), M = G[p,q,:,:]:
//   Trow = M v, Tcol = M^T v
//   J[p,q] = Trow.v ; J[q,p] = Tcol.v            (exclusive writes)
//   K[p,:] += v_q * Trow ; K[q,:] += v_p * Tcol  (atomicAdd)
// MODE 0: read fp32 G. MODE 1: read fp32 G, also write bf16 copy Gb.
// MODE 2: read bf16 Gb (84 MB/iter, L3-resident).
// Early-exits when SCF has converged (J/K already hold the fixed point... 
// they're stale-zero then, but buildF/eig also skip, so nothing reads them).
// ---------------------------------------------------------------------------
template <int MODE>
__global__ __launch_bounds__(256)
void k_contract(const float* __restrict__ G, unsigned short* __restrict__ Gb,
                const float* __restrict__ v,
                float* __restrict__ J, float* __restrict__ K,
                const int* __restrict__ conv)
{
    if (MODE != 1) { if (*conv) return; }   // uniform: all threads read same addr
    __shared__ float Ms[N * 97];   // stride 97: conflict-free row AND col dots
    __shared__ float vs[N];
    __shared__ float rsh[N];
    __shared__ float csh[N];
    const int tid = threadIdx.x;
    const int b   = blockIdx.x;
    // decode b -> (p,q), p<=q
    int p = (int)((193.0 - sqrt(37249.0 - 8.0 * (double)b)) * 0.5);
    if (p > 95) p = 95;
    if (p < 0) p = 0;
    while (p * 96 - p * (p - 1) / 2 > b) --p;
    while ((p + 1) * 96 - (p + 1) * p / 2 <= b) ++p;
    const int q = p + (b - (p * 96 - p * (p - 1) / 2));
    const int pr = b;

    if (tid < N) vs[tid] = v[tid];
    if (MODE == 2) {
        const uint4* Gb4 = (const uint4*)(Gb + (size_t)pr * N2);
        for (int i = tid; i < N2 / 8; i += 256) {   // 8 bf16 per uint4
            uint4 u = Gb4[i];
            int r = i / 12, s0 = (i - r * 12) * 8;
            float* dst = &Ms[r * 97 + s0];
            dst[0] = bf2f(u.x & 0xFFFFu); dst[1] = bf2f(u.x >> 16);
            dst[2] = bf2f(u.y & 0xFFFFu); dst[3] = bf2f(u.y >> 16);
            dst[4] = bf2f(u.z & 0xFFFFu); dst[5] = bf2f(u.z >> 16);
            dst[6] = bf2f(u.w & 0xFFFFu); dst[7] = bf2f(u.w >> 16);
        }
    } else {
        const float4* G4 = (const float4*)(G + (size_t)(p * N + q) * N2);
        uint2* Gb2 = (MODE == 1) ? (uint2*)(Gb + (size_t)pr * N2) : nullptr;
        for (int k = tid; k < N2 / 4; k += 256) {
            float4 f = G4[k];
            int r = k / 24, s4 = (k - r * 24) * 4;
            float* dst = &Ms[r * 97 + s4];
            dst[0] = f.x; dst[1] = f.y; dst[2] = f.z; dst[3] = f.w;
            if (MODE == 1) {
                uint2 o;
                o.x = (unsigned)f2bf(f.x) | ((unsigned)f2bf(f.y) << 16);
                o.y = (unsigned)f2bf(f.z) | ((unsigned)f2bf(f.w) << 16);
                Gb2[k] = o;
            }
        }
    }
    __syncthreads();
    if (tid < N) {                 // row dot r=tid: Trow[r] = sum_s M[r][s] v[s]
        const float* row = &Ms[tid * 97];
        float acc = 0.f;
        #pragma unroll 8
        for (int s = 0; s < N; ++s) acc += row[s] * vs[s];
        atomicAdd(&K[p * N + tid], vs[q] * acc);
        rsh[tid] = acc * vs[tid];
    } else if (tid < 2 * N && p != q) {  // col dot s: Tcol[s] = sum_r M[r][s] v[r]
        const int s = tid - N;
        float acc = 0.f;
        #pragma unroll 8
        for (int r = 0; r < N; ++r) acc += Ms[r * 97 + s] * vs[r];
        atomicAdd(&K[q * N + s], vs[p] * acc);
        csh[s] = acc * vs[s];
    }
    __syncthreads();
    const int lane = tid & 63, wv = tid >> 6;
    if (wv == 0) {                 // J[p,q] = Trow.v
        float a = rsh[lane];
        if (lane < 32) a += rsh[lane + 64];
        #pragma unroll
        for (int o = 32; o; o >>= 1) a += __shfl_xor(a, o);
        if (lane == 0) J[p * N + q] = a;
    } else if (wv == 1 && p != q) { // J[q,p] = Tcol.v
        float a = csh[lane];
        if (lane < 32) a += csh[lane + 64];
        #pragma unroll
        for (int o = 32; o; o >>= 1) a += __shfl_xor(a, o);
        if (lane == 0) J[q * N + p] = a;
    }
}

// ---------------------------------------------------------------------------
// Block p: F[p,:] = H + 2J - K ; M1[p,:] = F[p,:] @ A.
// zeroD call (it=0) also resets the conv flag for this kernel_launch call.
// ---------------------------------------------------------------------------
__global__ __launch_bounds__(128)
void k_buildF(const float* __restrict__ J, const float* __restrict__ K,
              const float* __restrict__ H, const float* __restrict__ A,
              float* __restrict__ F, float* __restrict__ M1, int zeroD,
              int* __restrict__ conv)
{
    if (zeroD) {
        if (threadIdx.x == 0 && blockIdx.x == 0) *conv = 0;
    } else if (*conv) {
        return;   // fixed point reached: F/M1 already hold converged values
    }
    __shared__ float As[N * 97];
    __shared__ float Frow[N];
    const int p = blockIdx.x, tid = threadIdx.x;
    {   // stage A (stride 97 -> conflict-free column reads)
        const float4* A4 = (const float4*)A;
        for (int k = tid; k < N2 / 4; k += 128) {
            float4 f = A4[k];
            int r = k / 24, c4 = (k - r * 24) * 4;
            float* dst = &As[r * 97 + c4];
            dst[0] = f.x; dst[1] = f.y; dst[2] = f.z; dst[3] = f.w;
        }
    }
    if (tid < N) {
        float f = H[p * N + tid];
        if (!zeroD) f += 2.0f * J[p * N + tid] - K[p * N + tid];
        Frow[tid] = f;
        F[p * N + tid] = f;
    }
    __syncthreads();
    if (tid < N) {
        float acc = 0.f;
        for (int k = 0; k < N; ++k) acc += Frow[k] * As[k * 97 + tid];
        M1[p * N + tid] = acc;
    }
}

// ---------------------------------------------------------------------------
// Single-block eigensolver. Fp x = A(M1 x) (no Fp materialization).
// Lanczos (warm-started, full single-pass reorth) -> bisection -> fp64
// inverse iteration -> Ritz. New: sign-align u to previous u, write E every
// iteration, set *conv when max|du| < CONV_TOL (warm only).
// ---------------------------------------------------------------------------
__global__ __launch_bounds__(384)
void k_eig(const float* __restrict__ M1, const float* __restrict__ A,
           const float* __restrict__ F, const float* __restrict__ H,
           const float* __restrict__ Enuc,
           float* __restrict__ v_ws, float* __restrict__ u_ws,
           float* __restrict__ jk,   // J,K contiguous: 2*N2 floats to zero
           float* __restrict__ out, int cold, int m_max,
           int* __restrict__ conv)
{
    if (!cold && *conv) return;    // out already holds converged E

    __shared__ float  Ms[N * 97];          // M1
    __shared__ float  As[N * 97];          // A
    __shared__ float  V[M_COLD][N];
    __shared__ float  w[N];
    __shared__ float  ysh[N];
    __shared__ float  vn[N];
    __shared__ float  uold[N];
    __shared__ float  dsh[N];
    __shared__ float  alpha[M_COLD + 1];
    __shared__ float  beta[M_COLD + 1];
    __shared__ float  dred[M_COLD];
    __shared__ float  wsml[M_COLD];
    __shared__ double cp[M_COLD];
    __shared__ double dp[M_COLD];
    __shared__ float  s_scal[4];
    __shared__ int    s_meff, s_done;

    const int tid  = threadIdx.x;
    const int lane = tid & 63;
    const int wv   = tid >> 6;

    // zero J/K for next SCF iteration's k_contract (consumed already by buildF)
    for (int i = tid; i < 2 * N2; i += 384) jk[i] = 0.f;

    {   // stage M1 and A (stride 97)
        const float4* M14 = (const float4*)M1;
        const float4* A4  = (const float4*)A;
        for (int k = tid; k < N2 / 4; k += 384) {
            int r = k / 24, c4 = (k - r * 24) * 4;
            float4 f = M14[k];
            float* d = &Ms[r * 97 + c4];
            d[0] = f.x; d[1] = f.y; d[2] = f.z; d[3] = f.w;
            float4 g = A4[k];
            float* e = &As[r * 97 + c4];
            e[0] = g.x; e[1] = g.y; e[2] = g.z; e[3] = g.w;
        }
    }
    if (tid < N) {
        float x;
        if (cold) {   // deterministic generic start vector
            unsigned r = (unsigned)tid * 1103515245u + 12345u;
            r ^= r >> 13; r *= 2654435761u; r ^= r >> 16;
            x = (float)(r & 0xFFFFu) * (1.0f / 65536.0f) - 0.45f;
            uold[tid] = 0.f;
        } else {
            x = u_ws[tid];
            uold[tid] = x;
        }
        w[tid] = x;
    }
    if (tid == 0) { s_meff = m_max; s_done = 0; beta[0] = 0.f; }
    __syncthreads();
    if (wv == 0) {   // normalize w -> V[0]
        float x0 = w[lane];
        float x1 = (lane < 32) ? w[lane + 64] : 0.f;
        float a = x0 * x0 + x1 * x1;
        #pragma unroll
        for (int o = 32; o; o >>= 1) a += __shfl_xor(a, o);
        float ib = 1.0f / sqrtf(a);
        V[0][lane] = x0 * ib;
        if (lane < 32) V[0][lane + 64] = x1 * ib;
    }
    __syncthreads();

    // ---------------- Lanczos: Fp x = A (M1 x) ----------------
    for (int j = 0; j < m_max; ++j) {
        if (s_done) break;
        const int i = tid >> 2, c = tid & 3;
        {   // y = Ms * V[j]
            const float* qv  = &V[j][0];
            const float* row = &Ms[i * 97 + c * 24];
            float p = 0.f;
            #pragma unroll
            for (int k = 0; k < 24; ++k) p += row[k] * qv[c * 24 + k];
            p += __shfl_xor(p, 1);
            p += __shfl_xor(p, 2);
            if (c == 0) ysh[i] = p;
        }
        __syncthreads();
        {   // w = As * y
            const float* row = &As[i * 97 + c * 24];
            float p = 0.f;
            #pragma unroll
            for (int k = 0; k < 24; ++k) p += row[k] * ysh[c * 24 + k];
            p += __shfl_xor(p, 1);
            p += __shfl_xor(p, 2);
            if (c == 0) w[i] = p;
        }
        __syncthreads();
        // dred[k] = <V[k], w>, alpha[j] = dred[j]
        for (int k = wv; k <= j; k += 6) {
            float a = V[k][lane] * w[lane];
            if (lane < 32) a += V[k][lane + 64] * w[lane + 64];
            #pragma unroll
            for (int o = 32; o; o >>= 1) a += __shfl_xor(a, o);
            if (lane == 0) { dred[k] = a; if (k == j) alpha[j] = a; }
        }
        __syncthreads();
        if (j + 1 == m_max) break;
        if (wv == 0) {   // orthogonalize, norm, V[j+1]
            float x0 = w[lane];
            float x1 = (lane < 32) ? w[lane + 64] : 0.f;
            for (int k = 0; k <= j; ++k) {
                float d = dred[k];
                x0 -= d * V[k][lane];
                if (lane < 32) x1 -= d * V[k][lane + 64];
            }
            float a = x0 * x0 + x1 * x1;
            #pragma unroll
            for (int o = 32; o; o >>= 1) a += __shfl_xor(a, o);
            float b = sqrtf(a);
            if (lane == 0) beta[j + 1] = b;
            if (b < 1e-5f) {
                if (lane == 0) { s_meff = j + 1; s_done = 1; }
            } else {
                float ib = 1.0f / b;
                V[j + 1][lane] = x0 * ib;
                if (lane < 32) V[j + 1][lane + 64] = x1 * ib;
            }
        }
        __syncthreads();
    }
    __syncthreads();
    const int m = s_meff;

    // ------------- smallest tridiag eigenvalue via 64-lane bisection ---------
    if (wv == 0) {
        float lo_l = 3e38f, hid = 3e38f;
        if (lane < m) {
            float bl = (lane > 0) ? fabsf(beta[lane]) : 0.f;
            float br = (lane + 1 < m) ? fabsf(beta[lane + 1]) : 0.f;
            lo_l = alpha[lane] - bl - br;
            hid  = alpha[lane];
        }
        #pragma unroll
        for (int o = 32; o; o >>= 1) {
            lo_l = fminf(lo_l, __shfl_xor(lo_l, o));
            hid  = fminf(hid,  __shfl_xor(hid,  o));
        }
        float lo = lo_l - 1e-5f, hi = hid + 1e-5f;
        for (int round = 0; round < 4; ++round) {
            float x = lo + (hi - lo) * (float)(lane + 1) * (1.0f / 65.0f);
            int cnt = 0;
            float qq = alpha[0] - x;
            if (qq < 0.f) cnt++;
            for (int i2 = 1; i2 < m; ++i2) {
                if (fabsf(qq) < 1e-25f) qq = (qq < 0.f) ? -1e-25f : 1e-25f;
                float bi = beta[i2];
                qq = (alpha[i2] - x) - bi * bi / qq;
                if (qq < 0.f) cnt++;
            }
            unsigned long long mask = __ballot(cnt >= 1);
            if (mask == 0ull) {
                lo = lo + (hi - lo) * (64.0f / 65.0f);
            } else {
                int f = __builtin_ctzll(mask);
                float xf  = lo + (hi - lo) * (float)(f + 1) * (1.0f / 65.0f);
                float xfm = lo + (hi - lo) * (float)(f)     * (1.0f / 65.0f);
                hi = xf; lo = xfm;
            }
        }
        if (lane == 0) s_scal[1] = 0.5f * (lo + hi);
    }
    __syncthreads();

    // ------------- fp64 inverse iteration, shift 1e-6 below lam_min ----------
    if (tid == 0) {
        if (m == 1) {
            wsml[0] = 1.0f;
        } else {
            double lam = (double)s_scal[1] - 1e-6;
            for (int pass = 0; pass < 2; ++pass) {
                double b0 = (double)alpha[0] - lam;
                if (fabs(b0) < 1e-18) b0 = (b0 < 0.0) ? -1e-18 : 1e-18;
                cp[0] = (double)beta[1] / b0;
                dp[0] = (pass ? (double)wsml[0] : 1.0) / b0;
                for (int i2 = 1; i2 < m; ++i2) {
                    double ai = (double)beta[i2];
                    double md = ((double)alpha[i2] - lam) - ai * cp[i2 - 1];
                    if (fabs(md) < 1e-18) md = (md < 0.0) ? -1e-18 : 1e-18;
                    cp[i2] = ((i2 + 1 < m) ? (double)beta[i2 + 1] : 0.0) / md;
                    double rhs = pass ? (double)wsml[i2] : 1.0;
                    dp[i2] = (rhs - ai * dp[i2 - 1]) / md;
                }
                for (int i2 = m - 2; i2 >= 0; --i2) dp[i2] -= cp[i2] * dp[i2 + 1];
                double nn = 0.0;
                for (int i2 = 0; i2 < m; ++i2) nn += dp[i2] * dp[i2];
                if (!(nn > 0.0) || isinf(nn)) {
                    for (int i2 = 0; i2 < m; ++i2) wsml[i2] = (i2 == 0) ? 1.0f : 0.0f;
                } else {
                    double inv = 1.0 / sqrt(nn);
                    for (int i2 = 0; i2 < m; ++i2) wsml[i2] = (float)(dp[i2] * inv);
                }
            }
        }
    }
    __syncthreads();

    // Ritz vector u = V^T wsml
    if (tid < N) {
        float acc = 0.f;
        for (int j = 0; j < m; ++j) acc += wsml[j] * V[j][tid];
        w[tid] = acc;
    }
    __syncthreads();
    if (wv == 0) {   // norm + sign-dot with previous u (one fused reduction)
        float x0 = w[lane], x1 = (lane < 32) ? w[lane + 64] : 0.f;
        float u0 = uold[lane], u1 = (lane < 32) ? uold[lane + 64] : 0.f;
        float a = x0 * x0 + x1 * x1;
        float d = x0 * u0 + x1 * u1;
        #pragma unroll
        for (int o = 32; o; o >>= 1) { a += __shfl_xor(a, o); d += __shfl_xor(d, o); }
        if (lane == 0) { s_scal[2] = sqrtf(a); s_scal[3] = d; }
    }
    __syncthreads();
    {
        const float sgn = (!cold && s_scal[3] < 0.f) ? -1.f : 1.f;
        if (tid < N) {
            float un = sgn * w[tid] / s_scal[2];
            w[tid] = un;
            u_ws[tid] = un;              // warm start for next SCF iteration
            dsh[tid] = fabsf(un - uold[tid]);
        }
    }
    __syncthreads();
    // v = A @ u (waves 0-1) ; convergence max-reduce (wave 3) in parallel
    if (tid < N) {
        const float* row = &As[tid * 97];
        float acc = 0.f;
        for (int k = 0; k < N; ++k) acc += row[k] * w[k];
        vn[tid] = acc;
        v_ws[tid] = acc;
    } else if (wv == 3) {
        float d0 = dsh[lane];
        if (lane < 32) d0 = fmaxf(d0, dsh[lane + 64]);
        #pragma unroll
        for (int o = 32; o; o >>= 1) d0 = fmaxf(d0, __shfl_xor(d0, o));
        if (lane == 0 && !cold && d0 < CONV_TOL) *conv = 1;
    }
    __syncthreads();
    // energy rows: w[i] = sum_k (F+H)[i,k] * vn[k]
    {
        const int i = tid >> 2, c = tid & 3;
        float p = 0.f;
        const int base = i * N + c * 24;
        #pragma unroll
        for (int k = 0; k < 24; ++k) p += (F[base + k] + H[base + k]) * vn[c * 24 + k];
        p += __shfl_xor(p, 1);
        p += __shfl_xor(p, 2);
        if (c == 0) w[i] = p;
    }
    __syncthreads();
    if (wv == 0) {
        float e = vn[lane] * w[lane];
        if (lane < 32) e += vn[lane + 64] * w[lane + 64];
        #pragma unroll
        for (int o = 32; o; o >>= 1) e += __shfl_xor(e, o);
        if (lane == 0) out[0] = e + Enuc[0];   // every executed iteration
    }
}

// ---------------------------------------------------------------------------
extern "C" void kernel_launch(void* const* d_in, const int* in_sizes, int n_in,
                              void* d_out, int out_size, void* d_ws, size_t ws_size,
                              hipStream_t stream)
{
    (void)in_sizes; (void)n_in; (void)out_size;
    // inputs: D (zeros, unused), H, A, G, Enuc
    const float* H    = (const float*)d_in[1];
    const float* A    = (const float*)d_in[2];
    const float* G    = (const float*)d_in[3];
    const float* Enuc = (const float*)d_in[4];
    float* out = (float*)d_out;
    float* ws  = (float*)d_ws;
    float* v   = ws + OFF_V;
    float* u   = ws + OFF_U;
    float* F   = ws + OFF_F;
    float* M1  = ws + OFF_M1;
    float* J   = ws + OFF_J;
    float* K   = ws + OFF_K;
    int*   conv = (int*)(ws + OFF_CONV);
    unsigned short* Gb = (unsigned short*)(ws + OFF_GB);
    const bool bf16ok = ws_size >= NEED_BF16_BYTES;

    for (int it = 0; it < 20; ++it) {
        if (it > 0) {
            if (!bf16ok)
                k_contract<0><<<NPAIR_SYM, 256, 0, stream>>>(G, Gb, v, J, K, conv);
            else if (it == 1)
                k_contract<1><<<NPAIR_SYM, 256, 0, stream>>>(G, Gb, v, J, K, conv);
            else
                k_contract<2><<<NPAIR_SYM, 256, 0, stream>>>(G, Gb, v, J, K, conv);
        }
        k_buildF<<<96, 128, 0, stream>>>(J, K, H, A, F, M1, it == 0 ? 1 : 0, conv);
        k_eig<<<1, 384, 0, stream>>>(M1, A, F, H, Enuc, v, u, J, out,
                                     it == 0 ? 1 : 0,
                                     it == 0 ? M_COLD : M_WARM,
                                     conv);
    }
}

// Round 7
// 413.112 us; speedup vs baseline: 9.5020x; 1.9805x over previous
//
#include <hip/hip_runtime.h>
#include <math.h>

#define N   96
#define N2  9216
#define NPAIR_SYM 4656     // 96*97/2 (p<=q) pair-blocks of G

#define M_COLD 24
#define M_WARM 8
#define CONV_TOL 2e-3f
#define CONTRACT_GRID 1024

// d_ws layout (float offsets)
#define OFF_V    0                 // 96: v = A@u (Cocc column; D = v v^T)
#define OFF_CONV 112               // 1 int: SCF converged flag
#define OFF_U    128               // 96: u (eigvec of Fp) warm start
#define OFF_J    256               // 9216: J
#define OFF_K    (OFF_J + N2)      // 9216: K (atomic-accumulated)
#define OFF_GB   (OFF_K + N2)      // bf16 G-half: 4656*9216 ushorts
#define NEED_BF16_BYTES ((size_t)OFF_GB * 4 + (size_t)NPAIR_SYM * N2 * 2)

__device__ __forceinline__ unsigned short f2bf(float x) {
    unsigned u = __float_as_uint(x);
    unsigned r = (u + 0x7FFFu + ((u >> 16) & 1u)) >> 16;
    return (unsigned short)r;
}
__device__ __forceinline__ float bf2f(unsigned h) {
    return __uint_as_float(h << 16);
}

// ---------------------------------------------------------------------------
// Grid-strided over pair-blocks (p<=q), M = G[p,q,:,:]:
//   Trow = M v, Tcol = M^T v
//   J[p,q] = Trow.v ; J[q,p] = Tcol.v            (exclusive writes)
//   K[p,:] += v_q * Trow ; K[q,:] += v_p * Tcol  (atomicAdd)
// MODE 0: read fp32 G. MODE 1: read fp32 G, also write bf16 copy Gb.
// MODE 2: read bf16 Gb (84 MB/iter, L3-resident).
// ---------------------------------------------------------------------------
template <int MODE>
__global__ __launch_bounds__(256)
void k_contract(const float* __restrict__ G, unsigned short* __restrict__ Gb,
                const float* __restrict__ v,
                float* __restrict__ J, float* __restrict__ K,
                const int* __restrict__ conv)
{
    if (MODE != 1) { if (*conv) return; }   // uniform load
    __shared__ float Ms[N * 97];   // stride 97: conflict-free row AND col dots
    __shared__ float vs[N];
    __shared__ float rsh[N];
    __shared__ float csh[N];
    const int tid = threadIdx.x;
    if (tid < N) vs[tid] = v[tid];

    for (int pr = blockIdx.x; pr < NPAIR_SYM; pr += (int)gridDim.x) {
        // decode pr -> (p,q), p<=q
        int p = (int)((193.0 - sqrt(37249.0 - 8.0 * (double)pr)) * 0.5);
        if (p > 95) p = 95;
        if (p < 0) p = 0;
        while (p * 96 - p * (p - 1) / 2 > pr) --p;
        while ((p + 1) * 96 - (p + 1) * p / 2 <= pr) ++p;
        const int q = p + (pr - (p * 96 - p * (p - 1) / 2));

        __syncthreads();   // Ms/rsh/csh reusable; vs visible (1st iter)
        if (MODE == 2) {
            const uint4* Gb4 = (const uint4*)(Gb + (size_t)pr * N2);
            for (int i = tid; i < N2 / 8; i += 256) {   // 8 bf16 per uint4
                uint4 u = Gb4[i];
                int r = i / 12, s0 = (i - r * 12) * 8;
                float* dst = &Ms[r * 97 + s0];
                dst[0] = bf2f(u.x & 0xFFFFu); dst[1] = bf2f(u.x >> 16);
                dst[2] = bf2f(u.y & 0xFFFFu); dst[3] = bf2f(u.y >> 16);
                dst[4] = bf2f(u.z & 0xFFFFu); dst[5] = bf2f(u.z >> 16);
                dst[6] = bf2f(u.w & 0xFFFFu); dst[7] = bf2f(u.w >> 16);
            }
        } else {
            const float4* G4 = (const float4*)(G + (size_t)(p * N + q) * N2);
            uint2* Gb2 = (MODE == 1) ? (uint2*)(Gb + (size_t)pr * N2) : nullptr;
            for (int k = tid; k < N2 / 4; k += 256) {
                float4 f = G4[k];
                int r = k / 24, s4 = (k - r * 24) * 4;
                float* dst = &Ms[r * 97 + s4];
                dst[0] = f.x; dst[1] = f.y; dst[2] = f.z; dst[3] = f.w;
                if (MODE == 1) {
                    uint2 o;
                    o.x = (unsigned)f2bf(f.x) | ((unsigned)f2bf(f.y) << 16);
                    o.y = (unsigned)f2bf(f.z) | ((unsigned)f2bf(f.w) << 16);
                    Gb2[k] = o;
                }
            }
        }
        __syncthreads();
        if (tid < N) {                 // row dot r=tid: Trow[r] = sum_s M[r][s] v[s]
            const float* row = &Ms[tid * 97];
            float acc = 0.f;
            #pragma unroll 8
            for (int s = 0; s < N; ++s) acc += row[s] * vs[s];
            atomicAdd(&K[p * N + tid], vs[q] * acc);
            rsh[tid] = acc * vs[tid];
        } else if (tid < 2 * N && p != q) {  // col dot s: Tcol[s] = sum_r M[r][s] v[r]
            const int s = tid - N;
            float acc = 0.f;
            #pragma unroll 8
            for (int r = 0; r < N; ++r) acc += Ms[r * 97 + s] * vs[r];
            atomicAdd(&K[q * N + s], vs[p] * acc);
            csh[s] = acc * vs[s];
        }
        __syncthreads();
        const int lane = tid & 63, wv = tid >> 6;
        if (wv == 0) {                 // J[p,q] = Trow.v
            float a = rsh[lane];
            if (lane < 32) a += rsh[lane + 64];
            #pragma unroll
            for (int o = 32; o; o >>= 1) a += __shfl_xor(a, o);
            if (lane == 0) J[p * N + q] = a;
        } else if (wv == 1 && p != q) { // J[q,p] = Tcol.v
            float a = csh[lane];
            if (lane < 32) a += csh[lane + 64];
            #pragma unroll
            for (int o = 32; o; o >>= 1) a += __shfl_xor(a, o);
            if (lane == 0) J[q * N + p] = a;
        }
    }
}

// ---------------------------------------------------------------------------
// Single-block fused F-build + eigensolver + energy.
//   phase 0: Fs = H (+ 2J - K) in LDS; stage As; zero J/K for next contract
//   Lanczos: Fp x = A (F (A x)) -- three LDS matvecs/step (no M1, no k_AM,
//            no k_buildF); single-pass full reorth; warm-started.
//   bisection (lowest tridiag eigval) -> fp64 inverse iteration -> Ritz u
//   v = A u ; conv check max|du| < CONV_TOL ; E = v'(F+H)v + Enuc (written
//   every executed iteration, so out retains converged E after skip).
// ---------------------------------------------------------------------------
__global__ __launch_bounds__(384)
void k_eig(const float* __restrict__ J, const float* __restrict__ K,
           const float* __restrict__ A, const float* __restrict__ H,
           const float* __restrict__ Enuc,
           float* __restrict__ v_ws, float* __restrict__ u_ws,
           float* __restrict__ jk,   // J,K contiguous: 2*N2 floats to zero
           float* __restrict__ out, int cold, int m_max,
           int* __restrict__ conv)
{
    if (!cold && *conv) return;    // out already holds converged E

    __shared__ float  Fs[N * 97];          // F = H + 2J - K
    __shared__ float  As[N * 97];          // A
    __shared__ float  V[M_COLD][N];
    __shared__ float  w[N];
    __shared__ float  t1[N];
    __shared__ float  t2[N];
    __shared__ float  vn[N];
    __shared__ float  uold[N];
    __shared__ float  dsh[N];
    __shared__ float  alpha[M_COLD + 1];
    __shared__ float  beta[M_COLD + 1];
    __shared__ float  dred[M_COLD];
    __shared__ float  wsml[M_COLD];
    __shared__ double cp[M_COLD];
    __shared__ double dp[M_COLD];
    __shared__ float  s_scal[4];
    __shared__ int    s_meff, s_done;

    const int tid  = threadIdx.x;
    const int lane = tid & 63;
    const int wv   = tid >> 6;

    if (cold && tid == 0) *conv = 0;   // reset flag for this launch

    {   // stage As and Fs (float4)
        const float4* A4 = (const float4*)A;
        const float4* H4 = (const float4*)H;
        for (int k = tid; k < N2 / 4; k += 384) {
            int r = k / 24, c4 = (k - r * 24) * 4;
            float4 g = A4[k];
            float* e = &As[r * 97 + c4];
            e[0] = g.x; e[1] = g.y; e[2] = g.z; e[3] = g.w;
            float4 h = H4[k];
            float* f = &Fs[r * 97 + c4];
            if (cold) {
                f[0] = h.x; f[1] = h.y; f[2] = h.z; f[3] = h.w;
            } else {
                float4 jj = ((const float4*)J)[k];
                float4 kk = ((const float4*)K)[k];
                f[0] = h.x + 2.f * jj.x - kk.x;
                f[1] = h.y + 2.f * jj.y - kk.y;
                f[2] = h.z + 2.f * jj.z - kk.z;
                f[3] = h.w + 2.f * jj.w - kk.w;
            }
        }
    }
    if (tid < N) {
        float x;
        if (cold) {   // deterministic generic start vector
            unsigned r = (unsigned)tid * 1103515245u + 12345u;
            r ^= r >> 13; r *= 2654435761u; r ^= r >> 16;
            x = (float)(r & 0xFFFFu) * (1.0f / 65536.0f) - 0.45f;
            uold[tid] = 0.f;
        } else {
            x = u_ws[tid];
            uold[tid] = x;
        }
        w[tid] = x;
    }
    if (tid == 0) { s_meff = m_max; s_done = 0; beta[0] = 0.f; }
    __syncthreads();
    // zero J/K for the next SCF iteration's contract (Fs already holds F)
    for (int i = tid; i < 2 * N2; i += 384) jk[i] = 0.f;
    if (wv == 0) {   // normalize w -> V[0]
        float x0 = w[lane];
        float x1 = (lane < 32) ? w[lane + 64] : 0.f;
        float a = x0 * x0 + x1 * x1;
        #pragma unroll
        for (int o = 32; o; o >>= 1) a += __shfl_xor(a, o);
        float ib = 1.0f / sqrtf(a);
        V[0][lane] = x0 * ib;
        if (lane < 32) V[0][lane + 64] = x1 * ib;
    }
    __syncthreads();

    // ---------------- Lanczos: Fp x = A (F (A x)), 5 barriers/step ----------
    const int mvi = tid >> 2, mvc = tid & 3;   // matvec split: 96 rows x 4 lanes
    for (int j = 0; j < m_max; ++j) {
        if (s_done) break;
        {   // t1 = As * V[j]
            const float* row = &As[mvi * 97 + mvc * 24];
            const float* src = &V[j][0];
            float p = 0.f;
            #pragma unroll
            for (int k = 0; k < 24; ++k) p += row[k] * src[mvc * 24 + k];
            p += __shfl_xor(p, 1);
            p += __shfl_xor(p, 2);
            if (mvc == 0) t1[mvi] = p;
        }
        __syncthreads();
        {   // t2 = Fs * t1
            const float* row = &Fs[mvi * 97 + mvc * 24];
            float p = 0.f;
            #pragma unroll
            for (int k = 0; k < 24; ++k) p += row[k] * t1[mvc * 24 + k];
            p += __shfl_xor(p, 1);
            p += __shfl_xor(p, 2);
            if (mvc == 0) t2[mvi] = p;
        }
        __syncthreads();
        {   // w = As * t2
            const float* row = &As[mvi * 97 + mvc * 24];
            float p = 0.f;
            #pragma unroll
            for (int k = 0; k < 24; ++k) p += row[k] * t2[mvc * 24 + k];
            p += __shfl_xor(p, 1);
            p += __shfl_xor(p, 2);
            if (mvc == 0) w[mvi] = p;
        }
        __syncthreads();
        // dred[k] = <V[k], w>, alpha[j] = dred[j]
        for (int k = wv; k <= j; k += 6) {
            float a = V[k][lane] * w[lane];
            if (lane < 32) a += V[k][lane + 64] * w[lane + 64];
            #pragma unroll
            for (int o = 32; o; o >>= 1) a += __shfl_xor(a, o);
            if (lane == 0) { dred[k] = a; if (k == j) alpha[j] = a; }
        }
        __syncthreads();
        if (j + 1 == m_max) break;
        if (wv == 0) {   // orthogonalize, norm, V[j+1]
            float x0 = w[lane];
            float x1 = (lane < 32) ? w[lane + 64] : 0.f;
            for (int k = 0; k <= j; ++k) {
                float d = dred[k];
                x0 -= d * V[k][lane];
                if (lane < 32) x1 -= d * V[k][lane + 64];
            }
            float a = x0 * x0 + x1 * x1;
            #pragma unroll
            for (int o = 32; o; o >>= 1) a += __shfl_xor(a, o);
            float b = sqrtf(a);
            if (lane == 0) beta[j + 1] = b;
            if (b < 1e-5f) {
                if (lane == 0) { s_meff = j + 1; s_done = 1; }
            } else {
                float ib = 1.0f / b;
                V[j + 1][lane] = x0 * ib;
                if (lane < 32) V[j + 1][lane + 64] = x1 * ib;
            }
        }
        __syncthreads();
    }
    __syncthreads();
    const int m = s_meff;

    // ------------- smallest tridiag eigenvalue via 64-lane bisection ---------
    if (wv == 0) {
        float lo_l = 3e38f, hid = 3e38f;
        if (lane < m) {
            float bl = (lane > 0) ? fabsf(beta[lane]) : 0.f;
            float br = (lane + 1 < m) ? fabsf(beta[lane + 1]) : 0.f;
            lo_l = alpha[lane] - bl - br;
            hid  = alpha[lane];
        }
        #pragma unroll
        for (int o = 32; o; o >>= 1) {
            lo_l = fminf(lo_l, __shfl_xor(lo_l, o));
            hid  = fminf(hid,  __shfl_xor(hid,  o));
        }
        float lo = lo_l - 1e-5f, hi = hid + 1e-5f;
        for (int round = 0; round < 4; ++round) {
            float x = lo + (hi - lo) * (float)(lane + 1) * (1.0f / 65.0f);
            int cnt = 0;
            float qq = alpha[0] - x;
            if (qq < 0.f) cnt++;
            for (int i2 = 1; i2 < m; ++i2) {
                if (fabsf(qq) < 1e-25f) qq = (qq < 0.f) ? -1e-25f : 1e-25f;
                float bi = beta[i2];
                qq = (alpha[i2] - x) - bi * bi / qq;
                if (qq < 0.f) cnt++;
            }
            unsigned long long mask = __ballot(cnt >= 1);
            if (mask == 0ull) {
                lo = lo + (hi - lo) * (64.0f / 65.0f);
            } else {
                int f = __builtin_ctzll(mask);
                float xf  = lo + (hi - lo) * (float)(f + 1) * (1.0f / 65.0f);
                float xfm = lo + (hi - lo) * (float)(f)     * (1.0f / 65.0f);
                hi = xf; lo = xfm;
            }
        }
        if (lane == 0) s_scal[1] = 0.5f * (lo + hi);
    }
    __syncthreads();

    // ------------- fp64 inverse iteration, shift 1e-6 below lam_min ----------
    if (tid == 0) {
        if (m == 1) {
            wsml[0] = 1.0f;
        } else {
            double lam = (double)s_scal[1] - 1e-6;
            for (int pass = 0; pass < 2; ++pass) {
                double b0 = (double)alpha[0] - lam;
                if (fabs(b0) < 1e-18) b0 = (b0 < 0.0) ? -1e-18 : 1e-18;
                cp[0] = (double)beta[1] / b0;
                dp[0] = (pass ? (double)wsml[0] : 1.0) / b0;
                for (int i2 = 1; i2 < m; ++i2) {
                    double ai = (double)beta[i2];
                    double md = ((double)alpha[i2] - lam) - ai * cp[i2 - 1];
                    if (fabs(md) < 1e-18) md = (md < 0.0) ? -1e-18 : 1e-18;
                    cp[i2] = ((i2 + 1 < m) ? (double)beta[i2 + 1] : 0.0) / md;
                    double rhs = pass ? (double)wsml[i2] : 1.0;
                    dp[i2] = (rhs - ai * dp[i2 - 1]) / md;
                }
                for (int i2 = m - 2; i2 >= 0; --i2) dp[i2] -= cp[i2] * dp[i2 + 1];
                double nn = 0.0;
                for (int i2 = 0; i2 < m; ++i2) nn += dp[i2] * dp[i2];
                if (!(nn > 0.0) || isinf(nn)) {
                    for (int i2 = 0; i2 < m; ++i2) wsml[i2] = (i2 == 0) ? 1.0f : 0.0f;
                } else {
                    double inv = 1.0 / sqrt(nn);
                    for (int i2 = 0; i2 < m; ++i2) wsml[i2] = (float)(dp[i2] * inv);
                }
            }
        }
    }
    __syncthreads();

    // Ritz vector u = V^T wsml
    if (tid < N) {
        float acc = 0.f;
        for (int j = 0; j < m; ++j) acc += wsml[j] * V[j][tid];
        w[tid] = acc;
    }
    __syncthreads();
    if (wv == 0) {   // norm + sign-dot with previous u (one fused reduction)
        float x0 = w[lane], x1 = (lane < 32) ? w[lane + 64] : 0.f;
        float u0 = uold[lane], u1 = (lane < 32) ? uold[lane + 64] : 0.f;
        float a = x0 * x0 + x1 * x1;
        float d = x0 * u0 + x1 * u1;
        #pragma unroll
        for (int o = 32; o; o >>= 1) { a += __shfl_xor(a, o); d += __shfl_xor(d, o); }
        if (lane == 0) { s_scal[2] = sqrtf(a); s_scal[3] = d; }
    }
    __syncthreads();
    {
        const float sgn = (!cold && s_scal[3] < 0.f) ? -1.f : 1.f;
        if (tid < N) {
            float un = sgn * w[tid] / s_scal[2];
            w[tid] = un;
            u_ws[tid] = un;              // warm start for next SCF iteration
            dsh[tid] = fabsf(un - uold[tid]);
        }
    }
    __syncthreads();
    // v = A @ u (threads 0..95) ; convergence max-reduce (wave 3) in parallel
    if (tid < N) {
        const float* row = &As[tid * 97];
        float acc = 0.f;
        for (int k = 0; k < N; ++k) acc += row[k] * w[k];
        vn[tid] = acc;
        v_ws[tid] = acc;
    } else if (wv == 3) {
        float d0 = dsh[lane];
        if (lane < 32) d0 = fmaxf(d0, dsh[lane + 64]);
        #pragma unroll
        for (int o = 32; o; o >>= 1) d0 = fmaxf(d0, __shfl_xor(d0, o));
        if (lane == 0 && !cold && d0 < CONV_TOL) *conv = 1;
    }
    __syncthreads();
    // energy rows: w[i] = sum_k (Fs+H)[i,k] * vn[k]
    {
        const float* frow = &Fs[mvi * 97 + mvc * 24];
        const int base = mvi * N + mvc * 24;
        float p = 0.f;
        #pragma unroll
        for (int k = 0; k < 24; ++k) p += (frow[k] + H[base + k]) * vn[mvc * 24 + k];
        p += __shfl_xor(p, 1);
        p += __shfl_xor(p, 2);
        if (mvc == 0) w[mvi] = p;
    }
    __syncthreads();
    if (wv == 0) {
        float e = vn[lane] * w[lane];
        if (lane < 32) e += vn[lane + 64] * w[lane + 64];
        #pragma unroll
        for (int o = 32; o; o >>= 1) e += __shfl_xor(e, o);
        if (lane == 0) out[0] = e + Enuc[0];   // every executed iteration
    }
}

// ---------------------------------------------------------------------------
extern "C" void kernel_launch(void* const* d_in, const int* in_sizes, int n_in,
                              void* d_out, int out_size, void* d_ws, size_t ws_size,
                              hipStream_t stream)
{
    (void)in_sizes; (void)n_in; (void)out_size;
    // inputs: D (zeros, unused), H, A, G, Enuc
    const float* H    = (const float*)d_in[1];
    const float* A    = (const float*)d_in[2];
    const float* G    = (const float*)d_in[3];
    const float* Enuc = (const float*)d_in[4];
    float* out = (float*)d_out;
    float* ws  = (float*)d_ws;
    float* v   = ws + OFF_V;
    float* u   = ws + OFF_U;
    float* J   = ws + OFF_J;
    float* K   = ws + OFF_K;
    int*   conv = (int*)(ws + OFF_CONV);
    unsigned short* Gb = (unsigned short*)(ws + OFF_GB);
    const bool bf16ok = ws_size >= NEED_BF16_BYTES;

    for (int it = 0; it < 20; ++it) {
        if (it > 0) {
            if (!bf16ok)
                k_contract<0><<<CONTRACT_GRID, 256, 0, stream>>>(G, Gb, v, J, K, conv);
            else if (it == 1)
                k_contract<1><<<CONTRACT_GRID, 256, 0, stream>>>(G, Gb, v, J, K, conv);
            else
                k_contract<2><<<CONTRACT_GRID, 256, 0, stream>>>(G, Gb, v, J, K, conv);
        }
        k_eig<<<1, 384, 0, stream>>>(J, K, A, H, Enuc, v, u, J, out,
                                     it == 0 ? 1 : 0,
                                     it == 0 ? M_COLD : M_WARM,
                                     conv);
    }
}